// Round 12
// baseline (145.444 us; speedup 1.0000x reference)
//
#include <hip/hip_runtime.h>

#define LEAK 0.2f

static __device__ __forceinline__ float leaky(float e) { return e > 0.f ? e : LEAK * e; }

// bf16 helpers (RNE pack, cheap unpack)
static __device__ __forceinline__ unsigned f2bf(float f) {
    union { float f; unsigned u; } v; v.f = f;
    return (v.u + 0x7FFFu + ((v.u >> 16) & 1u)) >> 16;
}
static __device__ __forceinline__ float bflo(unsigned u) {
    union { unsigned x; float f; } v; v.x = u << 16; return v.f;
}
static __device__ __forceinline__ float bfhi(unsigned u) {
    union { unsigned x; float f; } v; v.x = u & 0xFFFF0000u; return v.f;
}

using bf16x8 = __attribute__((ext_vector_type(8))) short;
using f32x4 = __attribute__((ext_vector_type(4))) float;

// ---------------- prep: zero counts + detect edge dtype + pre-transpose W1/W2 ----------------
__global__ __launch_bounds__(256) void k_prep(int* __restrict__ counts, int n,
                                              const int* __restrict__ ei, int nwords_check,
                                              int* __restrict__ flag,
                                              const float* __restrict__ W1,
                                              unsigned short* __restrict__ Wt1,
                                              const float* __restrict__ W2,
                                              unsigned short* __restrict__ Wt2, int NB) {
    int bid = blockIdx.x;
    int t = threadIdx.x;
    if (bid == 0) {
        if (t < 64) {
            int bad = 0;
            for (int i = 1 + 2 * t; i < nwords_check; i += 128) bad |= (ei[i] != 0);
            unsigned long long anybad = __ballot(bad != 0);
            if (t == 0) *flag = (anybad == 0ULL) ? 1 : 0;  // 1 => int64 layout
        }
        return;
    }
    if (bid <= NB) {
        int i = (bid - 1) * 256 + t;
        if (i < n) counts[i] = 0;
        return;
    }
    if (bid <= NB + 4) {                 // W1: 128x128, quarter q covers 32 k
        int q = bid - (NB + 1);
        int c = t & 127, ksub = t >> 7;  // ksub 0..1
        int k0 = q * 32 + ksub * 16;
        union { unsigned short s[16]; uint4 v[2]; } u;
#pragma unroll
        for (int j = 0; j < 16; ++j) u.s[j] = (unsigned short)f2bf(W1[(size_t)(k0 + j) * 128 + c]);
        uint4* dst = (uint4*)(Wt1 + (size_t)c * 128 + k0);
        dst[0] = u.v[0];
        dst[1] = u.v[1];
        return;
    }
    {                                    // W2: 128x64, half q covers 64 k
        int q = bid - (NB + 5);
        int c = t & 63, ksub = t >> 6;   // ksub 0..3
        int k0 = q * 64 + ksub * 16;
        union { unsigned short s[16]; uint4 v[2]; } u;
#pragma unroll
        for (int j = 0; j < 16; ++j) u.s[j] = (unsigned short)f2bf(W2[(size_t)(k0 + j) * 64 + c]);
        uint4* dst = (uint4*)(Wt2 + (size_t)c * 128 + k0);
        dst[0] = u.v[0];
        dst[1] = u.v[1];
        return;
    }
}

// ---------------- CSR rank pass: r = atomicAdd(counts[d]), packed (r<<16|d) ----------------
__global__ __launch_bounds__(256) void k_rank(const int* __restrict__ ei,
                                              const int* __restrict__ flag,
                                              int* __restrict__ counts,
                                              int* __restrict__ rankd,
                                              int* __restrict__ srcv, int E) {
    int base = (blockIdx.x * 256 + threadIdx.x) * 4;
    if (base >= E) return;
    int is64 = *flag;
    if (base + 3 < E) {
        int s0, s1, s2, s3, d0, d1, d2, d3;
        if (is64) {
            const uint4* ps = (const uint4*)(ei + 2 * (size_t)base);
            uint4 a = ps[0], b = ps[1];
            const uint4* pd = (const uint4*)(ei + 2 * ((size_t)E + base));
            uint4 c = pd[0], e4 = pd[1];
            s0 = a.x; s1 = a.z; s2 = b.x; s3 = b.z;
            d0 = c.x; d1 = c.z; d2 = e4.x; d3 = e4.z;
        } else {
            int4 a = *(const int4*)(ei + base);
            int4 b = *(const int4*)(ei + (size_t)E + base);
            s0 = a.x; s1 = a.y; s2 = a.z; s3 = a.w;
            d0 = b.x; d1 = b.y; d2 = b.z; d3 = b.w;
        }
        int r0 = atomicAdd(&counts[d0], 1);
        int r1 = atomicAdd(&counts[d1], 1);
        int r2 = atomicAdd(&counts[d2], 1);
        int r3 = atomicAdd(&counts[d3], 1);
        *(int4*)(rankd + base) = make_int4((r0 << 16) | d0, (r1 << 16) | d1,
                                           (r2 << 16) | d2, (r3 << 16) | d3);
        *(int4*)(srcv + base) = make_int4(s0, s1, s2, s3);
    } else {
        for (int j = 0; j < 4 && base + j < E; ++j) {
            int e = base + j;
            int ss = is64 ? ei[2 * (size_t)e] : ei[e];
            int dd = is64 ? ei[2 * ((size_t)E + e)] : ei[(size_t)E + e];
            int r = atomicAdd(&counts[dd], 1);
            rankd[e] = (r << 16) | dd;
            srcv[e] = ss;
        }
    }
}

__global__ void k_scan1(const int* __restrict__ counts, int* __restrict__ incl,
                        int* __restrict__ bsums, int n) {
    __shared__ int s[256];
    int t = threadIdx.x;
    int g = blockIdx.x * 256 + t;
    int v = (g < n) ? counts[g] : 0;
    s[t] = v;
    __syncthreads();
    for (int off = 1; off < 256; off <<= 1) {
        int add = (t >= off) ? s[t - off] : 0;
        __syncthreads();
        s[t] += add;
        __syncthreads();
    }
    if (g < n) incl[g] = s[t];
    if (t == 255) bsums[blockIdx.x] = s[255];
}

// scan2+scan3 merged: every block re-scans the <=256 bsums in LDS, then
// adds its chunk's exclusive prefix. (saves one launch + gap)
__global__ void k_scan23(const int* __restrict__ incl, const int* __restrict__ bsums,
                         int* __restrict__ rowptr, int n, int nb) {
    __shared__ int s[256];
    int t = threadIdx.x;
    int v = (t < nb) ? bsums[t] : 0;
    s[t] = v;
    __syncthreads();
    for (int off = 1; off < 256; off <<= 1) {
        int add = (t >= off) ? s[t - off] : 0;
        __syncthreads();
        s[t] += add;
        __syncthreads();
    }
    int pre = (blockIdx.x == 0) ? 0 : s[blockIdx.x - 1];
    int g = blockIdx.x * 256 + t;
    if (g < n) rowptr[g + 1] = incl[g] + pre;
    if (g == 0) rowptr[0] = 0;
}

// ---------------- MFMA GEMM1 + fused alpha, with co-scheduled place blocks ----------------
template <int F, bool AF32>
__global__ __launch_bounds__(256) void k_gemm_mfma(const void* __restrict__ Xv,
                                                   const unsigned short* __restrict__ Wt,
                                                   const float* __restrict__ asrc,
                                                   const float* __restrict__ adst,
                                                   unsigned short* __restrict__ Hb,
                                                   float* __restrict__ out_s,
                                                   float* __restrict__ out_d, int n,
                                                   int rowTiles,
                                                   const int* __restrict__ rankd,
                                                   const int* __restrict__ srcv,
                                                   const int* __restrict__ rowptr,
                                                   int* __restrict__ colv, int E) {
    constexpr int K = 128;
    constexpr int KP = K + 8;       // padded row length (shorts)
    constexpr int NT = F / 16;      // 16-col tiles per wave stripe
    __shared__ unsigned short wsT[F * KP];
    int t = threadIdx.x;

    if (blockIdx.x >= rowTiles) {   // ---- place role ----
        int base = ((blockIdx.x - rowTiles) * 256 + t) * 4;
        if (base >= E) return;
        if (base + 3 < E) {
            int4 rd = *(const int4*)(rankd + base);
            int4 sv = *(const int4*)(srcv + base);
            int p0 = rowptr[rd.x & 0xFFFF] + (rd.x >> 16);
            int p1 = rowptr[rd.y & 0xFFFF] + (rd.y >> 16);
            int p2 = rowptr[rd.z & 0xFFFF] + (rd.z >> 16);
            int p3 = rowptr[rd.w & 0xFFFF] + (rd.w >> 16);
            colv[p0] = sv.x;
            colv[p1] = sv.y;
            colv[p2] = sv.z;
            colv[p3] = sv.w;
        } else {
            for (int j = 0; j < 4 && base + j < E; ++j) {
                int e = base + j;
                int rd = rankd[e];
                colv[rowptr[rd & 0xFFFF] + (rd >> 16)] = srcv[e];
            }
        }
        return;
    }

    // ---- GEMM role ----
    int w = t >> 6, lane = t & 63;
    int lrow = lane & 15, kg = lane >> 4;  // kg in 0..3
    long long row0 = (long long)blockIdx.x * 64;

#pragma unroll
    for (int i = t; i < F * (K / 8); i += 256) {
        int c = i / (K / 8), j8 = i % (K / 8);
        uint4 v = ((const uint4*)(Wt + (size_t)c * K))[j8];
        *(uint4*)&wsT[c * KP + 8 * j8] = v;
    }
    __syncthreads();

    long long grow = row0 + w * 16 + lrow;
    bool rowok = grow < n;

    f32x4 acc[NT];
#pragma unroll
    for (int i = 0; i < NT; ++i) acc[i] = (f32x4){0.f, 0.f, 0.f, 0.f};

#pragma unroll
    for (int ks = 0; ks < K / 32; ++ks) {
        bf16x8 af;
        if constexpr (AF32) {
            const float* Xp = (const float*)Xv + grow * K + ks * 32 + kg * 8;
            float4 x0 = make_float4(0.f, 0.f, 0.f, 0.f), x1 = x0;
            if (rowok) {
                x0 = ((const float4*)Xp)[0];
                x1 = ((const float4*)Xp)[1];
            }
            af = (bf16x8){(short)f2bf(x0.x), (short)f2bf(x0.y), (short)f2bf(x0.z), (short)f2bf(x0.w),
                          (short)f2bf(x1.x), (short)f2bf(x1.y), (short)f2bf(x1.z), (short)f2bf(x1.w)};
        } else {
            uint4 u = make_uint4(0, 0, 0, 0);
            if (rowok) {
                const unsigned short* Xp = (const unsigned short*)Xv + grow * K + ks * 32 + kg * 8;
                u = *(const uint4*)Xp;
            }
            af = *(bf16x8*)&u;
        }
#pragma unroll
        for (int nt = 0; nt < NT; ++nt) {
            const unsigned short* bp = &wsT[(nt * 16 + lrow) * KP + ks * 32 + kg * 8];
            uint4 ub = *(const uint4*)bp;
            bf16x8 bf = *(bf16x8*)&ub;
            acc[nt] = __builtin_amdgcn_mfma_f32_16x16x32_bf16(af, bf, acc[nt], 0, 0, 0);
        }
    }

    // fused alpha
    {
        float ps[4] = {0.f, 0.f, 0.f, 0.f}, pd[4] = {0.f, 0.f, 0.f, 0.f};
#pragma unroll
        for (int nt = 0; nt < NT; ++nt) {
            float asv = asrc[nt * 16 + lrow];
            float adv = adst[nt * 16 + lrow];
#pragma unroll
            for (int i = 0; i < 4; ++i) {
                ps[i] = fmaf(acc[nt][i], asv, ps[i]);
                pd[i] = fmaf(acc[nt][i], adv, pd[i]);
            }
        }
#pragma unroll
        for (int off = 1; off < 16; off <<= 1) {
#pragma unroll
            for (int i = 0; i < 4; ++i) {
                ps[i] += __shfl_xor(ps[i], off);
                pd[i] += __shfl_xor(pd[i], off);
            }
        }
        if (lrow == 0) {
#pragma unroll
            for (int i = 0; i < 4; ++i) {
                long long r = row0 + w * 16 + kg * 4 + i;
                if (r < n) {
                    out_s[r] = ps[i];
                    out_d[r] = pd[i];
                }
            }
        }
    }

    int r0 = w * 16 + kg * 4;
#pragma unroll
    for (int nt = 0; nt < NT; ++nt) {
        int c = nt * 16 + lrow;
#pragma unroll
        for (int i = 0; i < 4; ++i) {
            long long r = row0 + r0 + i;
            if (r < n) Hb[r * F + c] = (unsigned short)f2bf(acc[nt][i]);
        }
    }
}

// ---------------- FUSED agg1 + gemm2 + alpha2 ----------------
// Block = 64 consecutive nodes (4 waves x 16 nodes sequential). Gather phase
// writes post-bias/ReLU out1 rows (bf16) to padded LDS At[64][136]; then the
// same block runs the 64x64 MFMA gemm2 from LDS (each wave's A-rows are the
// rows it just wrote -> only Wt2 staging needs the barrier) + fused alpha2.
// Removes the out1 HBM round trip and the separate gemm2 dispatch.
__global__ __launch_bounds__(256) void k_aggemm(const int* __restrict__ rowptr,
                                                const int* __restrict__ colv,
                                                const float* __restrict__ as_,
                                                const float* __restrict__ ad_,
                                                const unsigned* __restrict__ Hu,
                                                const float* __restrict__ bias,
                                                const unsigned short* __restrict__ Wt2,
                                                const float* __restrict__ a2s,
                                                const float* __restrict__ a2d,
                                                unsigned short* __restrict__ H2,
                                                float* __restrict__ out_s2,
                                                float* __restrict__ out_d2, int n) {
    constexpr int K = 128, KP = K + 8;
    __shared__ unsigned short At[64 * KP];   // out1 tile (bf16)
    __shared__ unsigned short Wt[64 * KP];   // W2^T (bf16, 64 cols x 128 k)
    int t = threadIdx.x;
    int w = t >> 6, lane = t & 63;

    // stage Wt2 -> LDS (linear uint4)
#pragma unroll
    for (int i = t; i < 64 * (K / 8); i += 256) {
        int c = i / (K / 8), j8 = i % (K / 8);
        uint4 v = ((const uint4*)(Wt2 + (size_t)c * K))[j8];
        *(uint4*)&Wt[c * KP + 8 * j8] = v;
    }

    long long node0 = (long long)blockIdx.x * 64 + w * 16;
    int grp = lane >> 4;       // 4 edge-groups (FG8=16)
    int fg = lane & 15;        // uint4 slot within row
    const uint4* __restrict__ H16 = (const uint4*)Hu;

    for (int ii = 0; ii < 16; ++ii) {
        long long node = node0 + ii;
        int ldsrow = w * 16 + ii;
        if (node >= n) {
            if (lane < 16) *(uint4*)&At[ldsrow * KP + lane * 8] = make_uint4(0, 0, 0, 0);
            continue;
        }
        int rs = rowptr[node], re = rowptr[node + 1];
        int deg = re - rs;
        float adi = ad_[node];
        float e_self = leaky(as_[node] + adi);

        int scol = (int)node;
        float e_l = -3.0e38f;
        if (lane < deg) {
            scol = colv[rs + lane];
            e_l = leaky(as_[scol] + adi);
        }
        float m = fmaxf(e_l, e_self);
        for (int base = 64; base < deg; base += 64) {
            if (base + lane < deg) m = fmaxf(m, leaky(as_[colv[rs + base + lane]] + adi));
        }
#pragma unroll
        for (int off = 32; off; off >>= 1) m = fmaxf(m, __shfl_xor(m, off));

        float p_l = (lane < deg) ? __expf(e_l - m) : 0.f;
        float ssum = p_l;
        for (int base = 64; base < deg; base += 64) {
            if (base + lane < deg) ssum += __expf(leaky(as_[colv[rs + base + lane]] + adi) - m);
        }
#pragma unroll
        for (int off = 32; off; off >>= 1) ssum += __shfl_xor(ssum, off);
        float pself = __expf(e_self - m);
        ssum += pself;
        float inv = 1.f / ssum;
        float w_l = p_l * inv;
        float wself = pself * inv;

        float a0, a1, a2, a3, a4, a5, a6, a7;
        {
            uint4 hv = H16[node * 16 + fg];
            float ws0 = (grp == 0) ? wself : 0.f;
            a0 = ws0 * bflo(hv.x); a1 = ws0 * bfhi(hv.x);
            a2 = ws0 * bflo(hv.y); a3 = ws0 * bfhi(hv.y);
            a4 = ws0 * bflo(hv.z); a5 = ws0 * bfhi(hv.z);
            a6 = ws0 * bflo(hv.w); a7 = ws0 * bfhi(hv.w);
        }
        int cnt = deg < 64 ? deg : 64;
        int cntr = (cnt + 15) & ~15;   // STEP = 16 (4 loads x GRP 4)
#pragma unroll 1
        for (int i = 0; i < cntr; i += 16) {
            int i0 = i + grp, i1 = i + 4 + grp, i2 = i + 8 + grp, i3 = i + 12 + grp;
            int s0 = __shfl(scol, i0), s1 = __shfl(scol, i1);
            int s2 = __shfl(scol, i2), s3 = __shfl(scol, i3);
            float w0 = __shfl(w_l, i0), w1 = __shfl(w_l, i1);
            float w2 = __shfl(w_l, i2), w3 = __shfl(w_l, i3);
            uint4 g0 = H16[(size_t)s0 * 16 + fg];
            uint4 g1 = H16[(size_t)s1 * 16 + fg];
            uint4 g2 = H16[(size_t)s2 * 16 + fg];
            uint4 g3 = H16[(size_t)s3 * 16 + fg];
            a0 = fmaf(w0, bflo(g0.x), a0); a1 = fmaf(w0, bfhi(g0.x), a1);
            a2 = fmaf(w0, bflo(g0.y), a2); a3 = fmaf(w0, bfhi(g0.y), a3);
            a4 = fmaf(w0, bflo(g0.z), a4); a5 = fmaf(w0, bfhi(g0.z), a5);
            a6 = fmaf(w0, bflo(g0.w), a6); a7 = fmaf(w0, bfhi(g0.w), a7);
            a0 = fmaf(w1, bflo(g1.x), a0); a1 = fmaf(w1, bfhi(g1.x), a1);
            a2 = fmaf(w1, bflo(g1.y), a2); a3 = fmaf(w1, bfhi(g1.y), a3);
            a4 = fmaf(w1, bflo(g1.z), a4); a5 = fmaf(w1, bfhi(g1.z), a5);
            a6 = fmaf(w1, bflo(g1.w), a6); a7 = fmaf(w1, bfhi(g1.w), a7);
            a0 = fmaf(w2, bflo(g2.x), a0); a1 = fmaf(w2, bfhi(g2.x), a1);
            a2 = fmaf(w2, bflo(g2.y), a2); a3 = fmaf(w2, bfhi(g2.y), a3);
            a4 = fmaf(w2, bflo(g2.z), a4); a5 = fmaf(w2, bfhi(g2.z), a5);
            a6 = fmaf(w2, bflo(g2.w), a6); a7 = fmaf(w2, bfhi(g2.w), a7);
            a0 = fmaf(w3, bflo(g3.x), a0); a1 = fmaf(w3, bfhi(g3.x), a1);
            a2 = fmaf(w3, bflo(g3.y), a2); a3 = fmaf(w3, bfhi(g3.y), a3);
            a4 = fmaf(w3, bflo(g3.z), a4); a5 = fmaf(w3, bfhi(g3.z), a5);
            a6 = fmaf(w3, bflo(g3.w), a6); a7 = fmaf(w3, bfhi(g3.w), a7);
        }
        for (int j = rs + 64; j < re; ++j) {
            int s = colv[j];
            float ww = __expf(leaky(as_[s] + adi) - m) * inv;
            float we = (grp == 0) ? ww : 0.f;
            uint4 g = H16[(size_t)s * 16 + fg];
            a0 = fmaf(we, bflo(g.x), a0); a1 = fmaf(we, bfhi(g.x), a1);
            a2 = fmaf(we, bflo(g.y), a2); a3 = fmaf(we, bfhi(g.y), a3);
            a4 = fmaf(we, bflo(g.z), a4); a5 = fmaf(we, bfhi(g.z), a5);
            a6 = fmaf(we, bflo(g.w), a6); a7 = fmaf(we, bfhi(g.w), a7);
        }
#pragma unroll
        for (int off = 16; off < 64; off <<= 1) {
            a0 += __shfl_xor(a0, off); a1 += __shfl_xor(a1, off);
            a2 += __shfl_xor(a2, off); a3 += __shfl_xor(a3, off);
            a4 += __shfl_xor(a4, off); a5 += __shfl_xor(a5, off);
            a6 += __shfl_xor(a6, off); a7 += __shfl_xor(a7, off);
        }
        if (grp == 0) {
            const float4* b4 = (const float4*)bias;
            float4 bv0 = b4[fg * 2], bv1 = b4[fg * 2 + 1];
            a0 = fmaxf(a0 + bv0.x, 0.f); a1 = fmaxf(a1 + bv0.y, 0.f);
            a2 = fmaxf(a2 + bv0.z, 0.f); a3 = fmaxf(a3 + bv0.w, 0.f);
            a4 = fmaxf(a4 + bv1.x, 0.f); a5 = fmaxf(a5 + bv1.y, 0.f);
            a6 = fmaxf(a6 + bv1.z, 0.f); a7 = fmaxf(a7 + bv1.w, 0.f);
            uint4 p;
            p.x = f2bf(a0) | (f2bf(a1) << 16);
            p.y = f2bf(a2) | (f2bf(a3) << 16);
            p.z = f2bf(a4) | (f2bf(a5) << 16);
            p.w = f2bf(a6) | (f2bf(a7) << 16);
            *(uint4*)&At[ldsrow * KP + fg * 8] = p;
        }
    }
    __syncthreads();

    // ---- gemm2 from LDS (64 rows x K=128 -> 64 cols) + alpha2 ----
    int lrow = lane & 15, kg = lane >> 4;
    long long row0 = (long long)blockIdx.x * 64;
    f32x4 acc[4];
#pragma unroll
    for (int i = 0; i < 4; ++i) acc[i] = (f32x4){0.f, 0.f, 0.f, 0.f};
#pragma unroll
    for (int ks = 0; ks < 4; ++ks) {
        uint4 ua = *(const uint4*)&At[(w * 16 + lrow) * KP + ks * 32 + kg * 8];
        bf16x8 af = *(bf16x8*)&ua;
#pragma unroll
        for (int nt = 0; nt < 4; ++nt) {
            uint4 ub = *(const uint4*)&Wt[(nt * 16 + lrow) * KP + ks * 32 + kg * 8];
            bf16x8 bf = *(bf16x8*)&ub;
            acc[nt] = __builtin_amdgcn_mfma_f32_16x16x32_bf16(af, bf, acc[nt], 0, 0, 0);
        }
    }
    {
        float ps[4] = {0.f, 0.f, 0.f, 0.f}, pd[4] = {0.f, 0.f, 0.f, 0.f};
#pragma unroll
        for (int nt = 0; nt < 4; ++nt) {
            float asv = a2s[nt * 16 + lrow];
            float adv = a2d[nt * 16 + lrow];
#pragma unroll
            for (int i = 0; i < 4; ++i) {
                ps[i] = fmaf(acc[nt][i], asv, ps[i]);
                pd[i] = fmaf(acc[nt][i], adv, pd[i]);
            }
        }
#pragma unroll
        for (int off = 1; off < 16; off <<= 1) {
#pragma unroll
            for (int i = 0; i < 4; ++i) {
                ps[i] += __shfl_xor(ps[i], off);
                pd[i] += __shfl_xor(pd[i], off);
            }
        }
        if (lrow == 0) {
#pragma unroll
            for (int i = 0; i < 4; ++i) {
                long long r = row0 + w * 16 + kg * 4 + i;
                if (r < n) {
                    out_s2[r] = ps[i];
                    out_d2[r] = pd[i];
                }
            }
        }
    }
    int r0 = w * 16 + kg * 4;
#pragma unroll
    for (int nt = 0; nt < 4; ++nt) {
        int c = nt * 16 + lrow;
#pragma unroll
        for (int i = 0; i < 4; ++i) {
            long long r = row0 + r0 + i;
            if (r < n) H2[r * 64 + c] = (unsigned short)f2bf(acc[nt][i]);
        }
    }
}

// ---------------- fused segment softmax + aggregation (layer 2, f32 out) ----------------
template <int F, bool RELU, bool OB>
__global__ __launch_bounds__(256) void k_agg(const int* __restrict__ rowptr,
                                             const int* __restrict__ colv,
                                             const float* __restrict__ as_,
                                             const float* __restrict__ ad_,
                                             const unsigned* __restrict__ Hu,
                                             const float* __restrict__ bias,
                                             void* __restrict__ OUT, int n) {
    constexpr int FG8 = F / 8;
    constexpr int GRP = 64 / FG8;
    int node = blockIdx.x * 4 + (threadIdx.x >> 6);
    int lane = threadIdx.x & 63;
    if (node >= n) return;
    int rs = rowptr[node], re = rowptr[node + 1];
    int deg = re - rs;
    float adi = ad_[node];
    float e_self = leaky(as_[node] + adi);

    int scol = node;
    float e_l = -3.0e38f;
    if (lane < deg) {
        scol = colv[rs + lane];
        e_l = leaky(as_[scol] + adi);
    }
    float m = fmaxf(e_l, e_self);
    for (int base = 64; base < deg; base += 64) {
        if (base + lane < deg) m = fmaxf(m, leaky(as_[colv[rs + base + lane]] + adi));
    }
#pragma unroll
    for (int off = 32; off; off >>= 1) m = fmaxf(m, __shfl_xor(m, off));

    float p_l = (lane < deg) ? __expf(e_l - m) : 0.f;
    float ssum = p_l;
    for (int base = 64; base < deg; base += 64) {
        if (base + lane < deg) ssum += __expf(leaky(as_[colv[rs + base + lane]] + adi) - m);
    }
#pragma unroll
    for (int off = 32; off; off >>= 1) ssum += __shfl_xor(ssum, off);
    float pself = __expf(e_self - m);
    ssum += pself;
    float inv = 1.f / ssum;
    float w_l = p_l * inv;
    float wself = pself * inv;

    int grp = lane / FG8;
    int fg = lane % FG8;
    const uint4* __restrict__ H16 = (const uint4*)Hu;
    float a0, a1, a2, a3, a4, a5, a6, a7;
    {
        uint4 hv = H16[(size_t)node * FG8 + fg];
        float ws0 = (grp == 0) ? wself : 0.f;
        a0 = ws0 * bflo(hv.x); a1 = ws0 * bfhi(hv.x);
        a2 = ws0 * bflo(hv.y); a3 = ws0 * bfhi(hv.y);
        a4 = ws0 * bflo(hv.z); a5 = ws0 * bfhi(hv.z);
        a6 = ws0 * bflo(hv.w); a7 = ws0 * bfhi(hv.w);
    }

    int cnt = deg < 64 ? deg : 64;
    constexpr int STEP = 4 * GRP;
    int cntr = (cnt + STEP - 1) / STEP * STEP;
#pragma unroll 1
    for (int i = 0; i < cntr; i += STEP) {
        int i0 = i + grp, i1 = i + GRP + grp, i2 = i + 2 * GRP + grp, i3 = i + 3 * GRP + grp;
        int s0 = __shfl(scol, i0), s1 = __shfl(scol, i1);
        int s2 = __shfl(scol, i2), s3 = __shfl(scol, i3);
        float w0 = __shfl(w_l, i0), w1 = __shfl(w_l, i1);
        float w2 = __shfl(w_l, i2), w3 = __shfl(w_l, i3);
        uint4 g0 = H16[(size_t)s0 * FG8 + fg];
        uint4 g1 = H16[(size_t)s1 * FG8 + fg];
        uint4 g2 = H16[(size_t)s2 * FG8 + fg];
        uint4 g3 = H16[(size_t)s3 * FG8 + fg];
        a0 = fmaf(w0, bflo(g0.x), a0); a1 = fmaf(w0, bfhi(g0.x), a1);
        a2 = fmaf(w0, bflo(g0.y), a2); a3 = fmaf(w0, bfhi(g0.y), a3);
        a4 = fmaf(w0, bflo(g0.z), a4); a5 = fmaf(w0, bfhi(g0.z), a5);
        a6 = fmaf(w0, bflo(g0.w), a6); a7 = fmaf(w0, bfhi(g0.w), a7);
        a0 = fmaf(w1, bflo(g1.x), a0); a1 = fmaf(w1, bfhi(g1.x), a1);
        a2 = fmaf(w1, bflo(g1.y), a2); a3 = fmaf(w1, bfhi(g1.y), a3);
        a4 = fmaf(w1, bflo(g1.z), a4); a5 = fmaf(w1, bfhi(g1.z), a5);
        a6 = fmaf(w1, bflo(g1.w), a6); a7 = fmaf(w1, bfhi(g1.w), a7);
        a0 = fmaf(w2, bflo(g2.x), a0); a1 = fmaf(w2, bfhi(g2.x), a1);
        a2 = fmaf(w2, bflo(g2.y), a2); a3 = fmaf(w2, bfhi(g2.y), a3);
        a4 = fmaf(w2, bflo(g2.z), a4); a5 = fmaf(w2, bfhi(g2.z), a5);
        a6 = fmaf(w2, bflo(g2.w), a6); a7 = fmaf(w2, bfhi(g2.w), a7);
        a0 = fmaf(w3, bflo(g3.x), a0); a1 = fmaf(w3, bfhi(g3.x), a1);
        a2 = fmaf(w3, bflo(g3.y), a2); a3 = fmaf(w3, bfhi(g3.y), a3);
        a4 = fmaf(w3, bflo(g3.z), a4); a5 = fmaf(w3, bfhi(g3.z), a5);
        a6 = fmaf(w3, bflo(g3.w), a6); a7 = fmaf(w3, bfhi(g3.w), a7);
    }
    for (int j = rs + 64; j < re; ++j) {
        int s = colv[j];
        float w = __expf(leaky(as_[s] + adi) - m) * inv;
        float we = (grp == 0) ? w : 0.f;
        uint4 g = H16[(size_t)s * FG8 + fg];
        a0 = fmaf(we, bflo(g.x), a0); a1 = fmaf(we, bfhi(g.x), a1);
        a2 = fmaf(we, bflo(g.y), a2); a3 = fmaf(we, bfhi(g.y), a3);
        a4 = fmaf(we, bflo(g.z), a4); a5 = fmaf(we, bfhi(g.z), a5);
        a6 = fmaf(we, bflo(g.w), a6); a7 = fmaf(we, bfhi(g.w), a7);
    }
#pragma unroll
    for (int off = FG8; off < 64; off <<= 1) {
        a0 += __shfl_xor(a0, off); a1 += __shfl_xor(a1, off);
        a2 += __shfl_xor(a2, off); a3 += __shfl_xor(a3, off);
        a4 += __shfl_xor(a4, off); a5 += __shfl_xor(a5, off);
        a6 += __shfl_xor(a6, off); a7 += __shfl_xor(a7, off);
    }
    if (grp == 0) {
        const float4* b4 = (const float4*)bias;
        float4 bv0 = b4[fg * 2], bv1 = b4[fg * 2 + 1];
        a0 += bv0.x; a1 += bv0.y; a2 += bv0.z; a3 += bv0.w;
        a4 += bv1.x; a5 += bv1.y; a6 += bv1.z; a7 += bv1.w;
        if (RELU) {
            a0 = fmaxf(a0, 0.f); a1 = fmaxf(a1, 0.f);
            a2 = fmaxf(a2, 0.f); a3 = fmaxf(a3, 0.f);
            a4 = fmaxf(a4, 0.f); a5 = fmaxf(a5, 0.f);
            a6 = fmaxf(a6, 0.f); a7 = fmaxf(a7, 0.f);
        }
        if (OB) {
            uint4 p;
            p.x = f2bf(a0) | (f2bf(a1) << 16);
            p.y = f2bf(a2) | (f2bf(a3) << 16);
            p.z = f2bf(a4) | (f2bf(a5) << 16);
            p.w = f2bf(a6) | (f2bf(a7) << 16);
            ((uint4*)OUT)[(size_t)node * FG8 + fg] = p;
        } else {
            float4* o4 = (float4*)((float*)OUT + (size_t)node * F + fg * 8);
            o4[0] = make_float4(a0, a1, a2, a3);
            o4[1] = make_float4(a4, a5, a6, a7);
        }
    }
}

// ---------------- host launch ----------------
extern "C" void kernel_launch(void* const* d_in, const int* in_sizes, int n_in,
                              void* d_out, int out_size, void* d_ws, size_t ws_size,
                              hipStream_t stream) {
    const float* x   = (const float*)d_in[0];
    const int*   ei  = (const int*)d_in[1];
    const float* W1  = (const float*)d_in[2];
    const float* a1s = (const float*)d_in[3];
    const float* a1d = (const float*)d_in[4];
    const float* b1  = (const float*)d_in[5];
    const float* W2  = (const float*)d_in[6];
    const float* a2s = (const float*)d_in[7];
    const float* a2d = (const float*)d_in[8];
    const float* b2  = (const float*)d_in[9];
    float* out = (float*)d_out;

    int N = in_sizes[0] / 128;   // 50000
    int E = in_sizes[1] / 2;     // 640000

    size_t off = 0;
    auto alloc = [&](size_t bytes) -> void* {
        off = (off + 255) & ~(size_t)255;
        void* p = (char*)d_ws + off;
        off += bytes;
        return p;
    };
    unsigned short* h  = (unsigned short*)alloc((size_t)N * 128 * 2);  // bf16 h1
    unsigned short* h2 = (unsigned short*)alloc((size_t)N * 64 * 2);   // bf16 h2
    unsigned short* Wt1 = (unsigned short*)alloc(128 * 128 * 2);
    unsigned short* Wt2 = (unsigned short*)alloc(64 * 128 * 2);
    float* as_    = (float*)alloc((size_t)N * 4);
    float* ad_    = (float*)alloc((size_t)N * 4);
    float* as2    = (float*)alloc((size_t)N * 4);
    float* ad2    = (float*)alloc((size_t)N * 4);
    int* counts   = (int*)alloc((size_t)N * 4);
    int* rowptr   = (int*)alloc((size_t)(N + 1) * 4);
    int* incl     = (int*)alloc((size_t)N * 4);
    int* bsums    = (int*)alloc(1024);
    int* colv     = (int*)alloc((size_t)E * 4);
    int* rankd    = (int*)alloc((size_t)E * 4);
    int* srcv     = (int*)alloc((size_t)E * 4);
    int* flag     = (int*)alloc(256);

    int NB = (N + 255) / 256;          // <= 256 required for in-LDS bsums scan
    int blocksN4 = (N + 3) / 4;
    int rowTiles = (N + 63) / 64;
    int blocksE4 = (E + 1023) / 1024;

    int nchk = 2 * E < 512 ? 2 * E : 512;
    k_prep<<<NB + 7, 256, 0, stream>>>(counts, N, ei, nchk, flag, W1, Wt1, W2, Wt2, NB);
    k_rank<<<blocksE4, 256, 0, stream>>>(ei, flag, counts, rankd, srcv, E);
    k_scan1<<<NB, 256, 0, stream>>>(counts, incl, bsums, N);
    k_scan23<<<NB, 256, 0, stream>>>(incl, bsums, rowptr, N, NB);

    // layer 1 GEMM co-scheduled with CSR place
    k_gemm_mfma<128, true><<<rowTiles + blocksE4, 256, 0, stream>>>(
        x, Wt1, a1s, a1d, h, as_, ad_, N, rowTiles, rankd, srcv, rowptr, colv, E);

    // fused agg1 + gemm2 + alpha2
    k_aggemm<<<rowTiles, 256, 0, stream>>>(rowptr, colv, as_, ad_, (const unsigned*)h,
                                           b1, Wt2, a2s, a2d, h2, as2, ad2, N);

    // layer 2 aggregation -> final output (f32)
    k_agg<64, false, false><<<blocksN4, 256, 0, stream>>>(rowptr, colv, as2, ad2,
                                                          (const unsigned*)h2, b2, out, N);
}

// Round 13
// 143.233 us; speedup vs baseline: 1.0154x; 1.0154x over previous
//
#include <hip/hip_runtime.h>

#define LEAK 0.2f

static __device__ __forceinline__ float leaky(float e) { return e > 0.f ? e : LEAK * e; }

// bf16 helpers (RNE pack, cheap unpack)
static __device__ __forceinline__ unsigned f2bf(float f) {
    union { float f; unsigned u; } v; v.f = f;
    return (v.u + 0x7FFFu + ((v.u >> 16) & 1u)) >> 16;
}
static __device__ __forceinline__ float bflo(unsigned u) {
    union { unsigned x; float f; } v; v.x = u << 16; return v.f;
}
static __device__ __forceinline__ float bfhi(unsigned u) {
    union { unsigned x; float f; } v; v.x = u & 0xFFFF0000u; return v.f;
}

using bf16x8 = __attribute__((ext_vector_type(8))) short;
using f32x4 = __attribute__((ext_vector_type(4))) float;

#define FMA8(A0, A1, A2, A3, A4, A5, A6, A7, W, G)              \
    A0 = fmaf(W, bflo(G.x), A0); A1 = fmaf(W, bfhi(G.x), A1);   \
    A2 = fmaf(W, bflo(G.y), A2); A3 = fmaf(W, bfhi(G.y), A3);   \
    A4 = fmaf(W, bflo(G.z), A4); A5 = fmaf(W, bfhi(G.z), A5);   \
    A6 = fmaf(W, bflo(G.w), A6); A7 = fmaf(W, bfhi(G.w), A7);

// ---------------- prep: zero counts + detect edge dtype + pre-transpose W1/W2 ----------------
__global__ __launch_bounds__(256) void k_prep(int* __restrict__ counts, int n,
                                              const int* __restrict__ ei, int nwords_check,
                                              int* __restrict__ flag,
                                              const float* __restrict__ W1,
                                              unsigned short* __restrict__ Wt1,
                                              const float* __restrict__ W2,
                                              unsigned short* __restrict__ Wt2, int NB) {
    int bid = blockIdx.x;
    int t = threadIdx.x;
    if (bid == 0) {
        if (t < 64) {
            int bad = 0;
            for (int i = 1 + 2 * t; i < nwords_check; i += 128) bad |= (ei[i] != 0);
            unsigned long long anybad = __ballot(bad != 0);
            if (t == 0) *flag = (anybad == 0ULL) ? 1 : 0;  // 1 => int64 layout
        }
        return;
    }
    if (bid <= NB) {
        int i = (bid - 1) * 256 + t;
        if (i < n) counts[i] = 0;
        return;
    }
    if (bid <= NB + 4) {                 // W1: 128x128, quarter q covers 32 k
        int q = bid - (NB + 1);
        int c = t & 127, ksub = t >> 7;  // ksub 0..1
        int k0 = q * 32 + ksub * 16;
        union { unsigned short s[16]; uint4 v[2]; } u;
#pragma unroll
        for (int j = 0; j < 16; ++j) u.s[j] = (unsigned short)f2bf(W1[(size_t)(k0 + j) * 128 + c]);
        uint4* dst = (uint4*)(Wt1 + (size_t)c * 128 + k0);
        dst[0] = u.v[0];
        dst[1] = u.v[1];
        return;
    }
    {                                    // W2: 128x64, half q covers 64 k
        int q = bid - (NB + 5);
        int c = t & 63, ksub = t >> 6;   // ksub 0..3
        int k0 = q * 64 + ksub * 16;
        union { unsigned short s[16]; uint4 v[2]; } u;
#pragma unroll
        for (int j = 0; j < 16; ++j) u.s[j] = (unsigned short)f2bf(W2[(size_t)(k0 + j) * 64 + c]);
        uint4* dst = (uint4*)(Wt2 + (size_t)c * 128 + k0);
        dst[0] = u.v[0];
        dst[1] = u.v[1];
        return;
    }
}

// ---------------- CSR rank pass: r = atomicAdd(counts[d]), packed (r<<16|d) ----------------
__global__ __launch_bounds__(256) void k_rank(const int* __restrict__ ei,
                                              const int* __restrict__ flag,
                                              int* __restrict__ counts,
                                              int* __restrict__ rankd,
                                              int* __restrict__ srcv, int E) {
    int base = (blockIdx.x * 256 + threadIdx.x) * 4;
    if (base >= E) return;
    int is64 = *flag;
    if (base + 3 < E) {
        int s0, s1, s2, s3, d0, d1, d2, d3;
        if (is64) {
            const uint4* ps = (const uint4*)(ei + 2 * (size_t)base);
            uint4 a = ps[0], b = ps[1];
            const uint4* pd = (const uint4*)(ei + 2 * ((size_t)E + base));
            uint4 c = pd[0], e4 = pd[1];
            s0 = a.x; s1 = a.z; s2 = b.x; s3 = b.z;
            d0 = c.x; d1 = c.z; d2 = e4.x; d3 = e4.z;
        } else {
            int4 a = *(const int4*)(ei + base);
            int4 b = *(const int4*)(ei + (size_t)E + base);
            s0 = a.x; s1 = a.y; s2 = a.z; s3 = a.w;
            d0 = b.x; d1 = b.y; d2 = b.z; d3 = b.w;
        }
        int r0 = atomicAdd(&counts[d0], 1);
        int r1 = atomicAdd(&counts[d1], 1);
        int r2 = atomicAdd(&counts[d2], 1);
        int r3 = atomicAdd(&counts[d3], 1);
        *(int4*)(rankd + base) = make_int4((r0 << 16) | d0, (r1 << 16) | d1,
                                           (r2 << 16) | d2, (r3 << 16) | d3);
        *(int4*)(srcv + base) = make_int4(s0, s1, s2, s3);
    } else {
        for (int j = 0; j < 4 && base + j < E; ++j) {
            int e = base + j;
            int ss = is64 ? ei[2 * (size_t)e] : ei[e];
            int dd = is64 ? ei[2 * ((size_t)E + e)] : ei[(size_t)E + e];
            int r = atomicAdd(&counts[dd], 1);
            rankd[e] = (r << 16) | dd;
            srcv[e] = ss;
        }
    }
}

__global__ void k_scan1(const int* __restrict__ counts, int* __restrict__ incl,
                        int* __restrict__ bsums, int n) {
    __shared__ int s[256];
    int t = threadIdx.x;
    int g = blockIdx.x * 256 + t;
    int v = (g < n) ? counts[g] : 0;
    s[t] = v;
    __syncthreads();
    for (int off = 1; off < 256; off <<= 1) {
        int add = (t >= off) ? s[t - off] : 0;
        __syncthreads();
        s[t] += add;
        __syncthreads();
    }
    if (g < n) incl[g] = s[t];
    if (t == 255) bsums[blockIdx.x] = s[255];
}

// scan2+scan3 merged: every block re-scans the <=256 bsums in LDS, then
// adds its chunk's exclusive prefix.
__global__ void k_scan23(const int* __restrict__ incl, const int* __restrict__ bsums,
                         int* __restrict__ rowptr, int n, int nb) {
    __shared__ int s[256];
    int t = threadIdx.x;
    int v = (t < nb) ? bsums[t] : 0;
    s[t] = v;
    __syncthreads();
    for (int off = 1; off < 256; off <<= 1) {
        int add = (t >= off) ? s[t - off] : 0;
        __syncthreads();
        s[t] += add;
        __syncthreads();
    }
    int pre = (blockIdx.x == 0) ? 0 : s[blockIdx.x - 1];
    int g = blockIdx.x * 256 + t;
    if (g < n) rowptr[g + 1] = incl[g] + pre;
    if (g == 0) rowptr[0] = 0;
}

// ---------------- MFMA GEMM + fused alpha, with co-scheduled place blocks ----------------
template <int F, bool AF32>
__global__ __launch_bounds__(256) void k_gemm_mfma(const void* __restrict__ Xv,
                                                   const unsigned short* __restrict__ Wt,
                                                   const float* __restrict__ asrc,
                                                   const float* __restrict__ adst,
                                                   unsigned short* __restrict__ Hb,
                                                   float* __restrict__ out_s,
                                                   float* __restrict__ out_d, int n,
                                                   int rowTiles,
                                                   const int* __restrict__ rankd,
                                                   const int* __restrict__ srcv,
                                                   const int* __restrict__ rowptr,
                                                   int* __restrict__ colv, int E) {
    constexpr int K = 128;
    constexpr int KP = K + 8;       // padded row length (shorts)
    constexpr int NT = F / 16;      // 16-col tiles per wave stripe
    __shared__ unsigned short wsT[F * KP];
    int t = threadIdx.x;

    if (blockIdx.x >= rowTiles) {   // ---- place role (latency-bound scatter) ----
        int base = ((blockIdx.x - rowTiles) * 256 + t) * 4;
        if (base >= E) return;
        if (base + 3 < E) {
            int4 rd = *(const int4*)(rankd + base);
            int4 sv = *(const int4*)(srcv + base);
            int p0 = rowptr[rd.x & 0xFFFF] + (rd.x >> 16);
            int p1 = rowptr[rd.y & 0xFFFF] + (rd.y >> 16);
            int p2 = rowptr[rd.z & 0xFFFF] + (rd.z >> 16);
            int p3 = rowptr[rd.w & 0xFFFF] + (rd.w >> 16);
            colv[p0] = sv.x;
            colv[p1] = sv.y;
            colv[p2] = sv.z;
            colv[p3] = sv.w;
        } else {
            for (int j = 0; j < 4 && base + j < E; ++j) {
                int e = base + j;
                int rd = rankd[e];
                colv[rowptr[rd & 0xFFFF] + (rd >> 16)] = srcv[e];
            }
        }
        return;
    }

    // ---- GEMM role ----
    int w = t >> 6, lane = t & 63;
    int lrow = lane & 15, kg = lane >> 4;  // kg in 0..3
    long long row0 = (long long)blockIdx.x * 64;

#pragma unroll
    for (int i = t; i < F * (K / 8); i += 256) {
        int c = i / (K / 8), j8 = i % (K / 8);
        uint4 v = ((const uint4*)(Wt + (size_t)c * K))[j8];
        *(uint4*)&wsT[c * KP + 8 * j8] = v;
    }
    __syncthreads();

    long long grow = row0 + w * 16 + lrow;
    bool rowok = grow < n;

    f32x4 acc[NT];
#pragma unroll
    for (int i = 0; i < NT; ++i) acc[i] = (f32x4){0.f, 0.f, 0.f, 0.f};

#pragma unroll
    for (int ks = 0; ks < K / 32; ++ks) {
        bf16x8 af;
        if constexpr (AF32) {
            const float* Xp = (const float*)Xv + grow * K + ks * 32 + kg * 8;
            float4 x0 = make_float4(0.f, 0.f, 0.f, 0.f), x1 = x0;
            if (rowok) {
                x0 = ((const float4*)Xp)[0];
                x1 = ((const float4*)Xp)[1];
            }
            af = (bf16x8){(short)f2bf(x0.x), (short)f2bf(x0.y), (short)f2bf(x0.z), (short)f2bf(x0.w),
                          (short)f2bf(x1.x), (short)f2bf(x1.y), (short)f2bf(x1.z), (short)f2bf(x1.w)};
        } else {
            uint4 u = make_uint4(0, 0, 0, 0);
            if (rowok) {
                const unsigned short* Xp = (const unsigned short*)Xv + grow * K + ks * 32 + kg * 8;
                u = *(const uint4*)Xp;
            }
            af = *(bf16x8*)&u;
        }
#pragma unroll
        for (int nt = 0; nt < NT; ++nt) {
            const unsigned short* bp = &wsT[(nt * 16 + lrow) * KP + ks * 32 + kg * 8];
            uint4 ub = *(const uint4*)bp;
            bf16x8 bf = *(bf16x8*)&ub;
            acc[nt] = __builtin_amdgcn_mfma_f32_16x16x32_bf16(af, bf, acc[nt], 0, 0, 0);
        }
    }

    // fused alpha
    {
        float ps[4] = {0.f, 0.f, 0.f, 0.f}, pd[4] = {0.f, 0.f, 0.f, 0.f};
#pragma unroll
        for (int nt = 0; nt < NT; ++nt) {
            float asv = asrc[nt * 16 + lrow];
            float adv = adst[nt * 16 + lrow];
#pragma unroll
            for (int i = 0; i < 4; ++i) {
                ps[i] = fmaf(acc[nt][i], asv, ps[i]);
                pd[i] = fmaf(acc[nt][i], adv, pd[i]);
            }
        }
#pragma unroll
        for (int off = 1; off < 16; off <<= 1) {
#pragma unroll
            for (int i = 0; i < 4; ++i) {
                ps[i] += __shfl_xor(ps[i], off);
                pd[i] += __shfl_xor(pd[i], off);
            }
        }
        if (lrow == 0) {
#pragma unroll
            for (int i = 0; i < 4; ++i) {
                long long r = row0 + w * 16 + kg * 4 + i;
                if (r < n) {
                    out_s[r] = ps[i];
                    out_d[r] = pd[i];
                }
            }
        }
    }

    int r0 = w * 16 + kg * 4;
#pragma unroll
    for (int nt = 0; nt < NT; ++nt) {
        int c = nt * 16 + lrow;
#pragma unroll
        for (int i = 0; i < 4; ++i) {
            long long r = row0 + r0 + i;
            if (r < n) Hb[r * F + c] = (unsigned short)f2bf(acc[nt][i]);
        }
    }
}

// ---------------- fused segment softmax + aggregation, TWO nodes per wave ----------------
// Doubles per-wave memory-level parallelism (independent softmax chains + 8
// gather loads in flight instead of 4). All A/B state explicitly named so
// everything stays in registers. Per-node arithmetic identical to 1-node
// version (same shfl trees, same order) -> bit-identical output.
template <int F, bool RELU, bool OB>
__global__ __launch_bounds__(256) void k_agg(const int* __restrict__ rowptr,
                                             const int* __restrict__ colv,
                                             const float* __restrict__ as_,
                                             const float* __restrict__ ad_,
                                             const unsigned* __restrict__ Hu,
                                             const float* __restrict__ bias,
                                             void* __restrict__ OUT, int n) {
    constexpr int FG8 = F / 8;       // uint4 slots per row (16 or 8)
    constexpr int GRP = 64 / FG8;    // edge-groups per wave (4 or 8)
    constexpr int STEP = 4 * GRP;    // edges per unrolled iter (4 loads)
    int wid = blockIdx.x * 4 + (threadIdx.x >> 6);
    int lane = threadIdx.x & 63;
    long long nA = (long long)wid * 2;
    if (nA >= n) return;
    long long nB = nA + 1;
    bool vB = nB < n;
    long long nBc = vB ? nB : nA;    // clamped for loads

    int rsA = rowptr[nA], reA = rowptr[nA + 1];
    int rsB = rowptr[nBc], reB = rowptr[nBc + 1];
    int degA = reA - rsA, degB = reB - rsB;
    float adiA = ad_[nA], adiB = ad_[nBc];
    float esA = leaky(as_[nA] + adiA);
    float esB = leaky(as_[nBc] + adiB);

    int scA = (int)nA, scB = (int)nBc;
    float eA = -3.0e38f, eB = -3.0e38f;
    if (lane < degA) scA = colv[rsA + lane];
    if (lane < degB) scB = colv[rsB + lane];
    if (lane < degA) eA = leaky(as_[scA] + adiA);
    if (lane < degB) eB = leaky(as_[scB] + adiB);

    float mA = fmaxf(eA, esA), mB = fmaxf(eB, esB);
    for (int base = 64; base < degA; base += 64)   // rare: deg > 64
        if (base + lane < degA) mA = fmaxf(mA, leaky(as_[colv[rsA + base + lane]] + adiA));
    for (int base = 64; base < degB; base += 64)
        if (base + lane < degB) mB = fmaxf(mB, leaky(as_[colv[rsB + base + lane]] + adiB));
#pragma unroll
    for (int off = 32; off; off >>= 1) {
        mA = fmaxf(mA, __shfl_xor(mA, off));
        mB = fmaxf(mB, __shfl_xor(mB, off));
    }

    float pA = (lane < degA) ? __expf(eA - mA) : 0.f;
    float pB = (lane < degB) ? __expf(eB - mB) : 0.f;
    float sA = pA, sB = pB;
    for (int base = 64; base < degA; base += 64)
        if (base + lane < degA) sA += __expf(leaky(as_[colv[rsA + base + lane]] + adiA) - mA);
    for (int base = 64; base < degB; base += 64)
        if (base + lane < degB) sB += __expf(leaky(as_[colv[rsB + base + lane]] + adiB) - mB);
#pragma unroll
    for (int off = 32; off; off >>= 1) {
        sA += __shfl_xor(sA, off);
        sB += __shfl_xor(sB, off);
    }
    float psA = __expf(esA - mA), psB = __expf(esB - mB);
    sA += psA;
    sB += psB;
    float invA = 1.f / sA, invB = 1.f / sB;
    float wA = pA * invA, wB = pB * invB;       // this lane's edge weight
    float wsA = psA * invA, wsB = psB * invB;   // self weights

    // ---- gather ----
    int grp = lane / FG8;
    int fg = lane % FG8;
    const uint4* __restrict__ H16 = (const uint4*)Hu;
    float a0A, a1A, a2A, a3A, a4A, a5A, a6A, a7A;
    float a0B, a1B, a2B, a3B, a4B, a5B, a6B, a7B;
    {
        uint4 hvA = H16[(size_t)nA * FG8 + fg];
        uint4 hvB = H16[(size_t)nBc * FG8 + fg];
        float w0A = (grp == 0) ? wsA : 0.f;
        float w0B = (grp == 0) ? wsB : 0.f;
        a0A = w0A * bflo(hvA.x); a1A = w0A * bfhi(hvA.x);
        a2A = w0A * bflo(hvA.y); a3A = w0A * bfhi(hvA.y);
        a4A = w0A * bflo(hvA.z); a5A = w0A * bfhi(hvA.z);
        a6A = w0A * bflo(hvA.w); a7A = w0A * bfhi(hvA.w);
        a0B = w0B * bflo(hvB.x); a1B = w0B * bfhi(hvB.x);
        a2B = w0B * bflo(hvB.y); a3B = w0B * bfhi(hvB.y);
        a4B = w0B * bflo(hvB.z); a5B = w0B * bfhi(hvB.z);
        a6B = w0B * bflo(hvB.w); a7B = w0B * bfhi(hvB.w);
    }

    int cntA = degA < 64 ? degA : 64;
    int cntB = degB < 64 ? degB : 64;
    int cntrA = (cntA + STEP - 1) / STEP * STEP;
    int cntrB = (cntB + STEP - 1) / STEP * STEP;
    int cntrM = cntrA > cntrB ? cntrA : cntrB;
#pragma unroll 1
    for (int i = 0; i < cntrM; i += STEP) {
        bool doA = i < cntrA, doB = i < cntrB;  // wave-uniform
        uint4 gA0, gA1, gA2, gA3, gB0, gB1, gB2, gB3;
        float wA0, wA1, wA2, wA3, wB0, wB1, wB2, wB3;
        if (doA) {
            int i0 = i + grp, i1 = i + GRP + grp, i2 = i + 2 * GRP + grp, i3 = i + 3 * GRP + grp;
            int s0 = __shfl(scA, i0), s1 = __shfl(scA, i1);
            int s2 = __shfl(scA, i2), s3 = __shfl(scA, i3);
            wA0 = __shfl(wA, i0); wA1 = __shfl(wA, i1);
            wA2 = __shfl(wA, i2); wA3 = __shfl(wA, i3);
            gA0 = H16[(size_t)s0 * FG8 + fg];
            gA1 = H16[(size_t)s1 * FG8 + fg];
            gA2 = H16[(size_t)s2 * FG8 + fg];
            gA3 = H16[(size_t)s3 * FG8 + fg];
        }
        if (doB) {
            int i0 = i + grp, i1 = i + GRP + grp, i2 = i + 2 * GRP + grp, i3 = i + 3 * GRP + grp;
            int s0 = __shfl(scB, i0), s1 = __shfl(scB, i1);
            int s2 = __shfl(scB, i2), s3 = __shfl(scB, i3);
            wB0 = __shfl(wB, i0); wB1 = __shfl(wB, i1);
            wB2 = __shfl(wB, i2); wB3 = __shfl(wB, i3);
            gB0 = H16[(size_t)s0 * FG8 + fg];
            gB1 = H16[(size_t)s1 * FG8 + fg];
            gB2 = H16[(size_t)s2 * FG8 + fg];
            gB3 = H16[(size_t)s3 * FG8 + fg];
        }
        if (doA) {
            FMA8(a0A, a1A, a2A, a3A, a4A, a5A, a6A, a7A, wA0, gA0)
            FMA8(a0A, a1A, a2A, a3A, a4A, a5A, a6A, a7A, wA1, gA1)
            FMA8(a0A, a1A, a2A, a3A, a4A, a5A, a6A, a7A, wA2, gA2)
            FMA8(a0A, a1A, a2A, a3A, a4A, a5A, a6A, a7A, wA3, gA3)
        }
        if (doB) {
            FMA8(a0B, a1B, a2B, a3B, a4B, a5B, a6B, a7B, wB0, gB0)
            FMA8(a0B, a1B, a2B, a3B, a4B, a5B, a6B, a7B, wB1, gB1)
            FMA8(a0B, a1B, a2B, a3B, a4B, a5B, a6B, a7B, wB2, gB2)
            FMA8(a0B, a1B, a2B, a3B, a4B, a5B, a6B, a7B, wB3, gB3)
        }
    }
    for (int j = rsA + 64; j < reA; ++j) {  // rare: deg > 64
        int s = colv[j];
        float w = __expf(leaky(as_[s] + adiA) - mA) * invA;
        float we = (grp == 0) ? w : 0.f;
        uint4 g = H16[(size_t)s * FG8 + fg];
        FMA8(a0A, a1A, a2A, a3A, a4A, a5A, a6A, a7A, we, g)
    }
    for (int j = rsB + 64; j < reB; ++j) {
        int s = colv[j];
        float w = __expf(leaky(as_[s] + adiB) - mB) * invB;
        float we = (grp == 0) ? w : 0.f;
        uint4 g = H16[(size_t)s * FG8 + fg];
        FMA8(a0B, a1B, a2B, a3B, a4B, a5B, a6B, a7B, we, g)
    }
    // combine edge-groups (commutative adds -> deterministic)
#pragma unroll
    for (int off = FG8; off < 64; off <<= 1) {
        a0A += __shfl_xor(a0A, off); a1A += __shfl_xor(a1A, off);
        a2A += __shfl_xor(a2A, off); a3A += __shfl_xor(a3A, off);
        a4A += __shfl_xor(a4A, off); a5A += __shfl_xor(a5A, off);
        a6A += __shfl_xor(a6A, off); a7A += __shfl_xor(a7A, off);
        a0B += __shfl_xor(a0B, off); a1B += __shfl_xor(a1B, off);
        a2B += __shfl_xor(a2B, off); a3B += __shfl_xor(a3B, off);
        a4B += __shfl_xor(a4B, off); a5B += __shfl_xor(a5B, off);
        a6B += __shfl_xor(a6B, off); a7B += __shfl_xor(a7B, off);
    }
    if (grp == 0) {
        const float4* b4 = (const float4*)bias;
        float4 bv0 = b4[fg * 2], bv1 = b4[fg * 2 + 1];
        a0A += bv0.x; a1A += bv0.y; a2A += bv0.z; a3A += bv0.w;
        a4A += bv1.x; a5A += bv1.y; a6A += bv1.z; a7A += bv1.w;
        a0B += bv0.x; a1B += bv0.y; a2B += bv0.z; a3B += bv0.w;
        a4B += bv1.x; a5B += bv1.y; a6B += bv1.z; a7B += bv1.w;
        if (RELU) {
            a0A = fmaxf(a0A, 0.f); a1A = fmaxf(a1A, 0.f);
            a2A = fmaxf(a2A, 0.f); a3A = fmaxf(a3A, 0.f);
            a4A = fmaxf(a4A, 0.f); a5A = fmaxf(a5A, 0.f);
            a6A = fmaxf(a6A, 0.f); a7A = fmaxf(a7A, 0.f);
            a0B = fmaxf(a0B, 0.f); a1B = fmaxf(a1B, 0.f);
            a2B = fmaxf(a2B, 0.f); a3B = fmaxf(a3B, 0.f);
            a4B = fmaxf(a4B, 0.f); a5B = fmaxf(a5B, 0.f);
            a6B = fmaxf(a6B, 0.f); a7B = fmaxf(a7B, 0.f);
        }
        if (OB) {
            uint4 p;
            p.x = f2bf(a0A) | (f2bf(a1A) << 16);
            p.y = f2bf(a2A) | (f2bf(a3A) << 16);
            p.z = f2bf(a4A) | (f2bf(a5A) << 16);
            p.w = f2bf(a6A) | (f2bf(a7A) << 16);
            ((uint4*)OUT)[(size_t)nA * FG8 + fg] = p;
            if (vB) {
                uint4 q;
                q.x = f2bf(a0B) | (f2bf(a1B) << 16);
                q.y = f2bf(a2B) | (f2bf(a3B) << 16);
                q.z = f2bf(a4B) | (f2bf(a5B) << 16);
                q.w = f2bf(a6B) | (f2bf(a7B) << 16);
                ((uint4*)OUT)[(size_t)nB * FG8 + fg] = q;
            }
        } else {
            float4* oA = (float4*)((float*)OUT + (size_t)nA * F + fg * 8);
            oA[0] = make_float4(a0A, a1A, a2A, a3A);
            oA[1] = make_float4(a4A, a5A, a6A, a7A);
            if (vB) {
                float4* oB = (float4*)((float*)OUT + (size_t)nB * F + fg * 8);
                oB[0] = make_float4(a0B, a1B, a2B, a3B);
                oB[1] = make_float4(a4B, a5B, a6B, a7B);
            }
        }
    }
}

// ---------------- host launch ----------------
extern "C" void kernel_launch(void* const* d_in, const int* in_sizes, int n_in,
                              void* d_out, int out_size, void* d_ws, size_t ws_size,
                              hipStream_t stream) {
    const float* x   = (const float*)d_in[0];
    const int*   ei  = (const int*)d_in[1];
    const float* W1  = (const float*)d_in[2];
    const float* a1s = (const float*)d_in[3];
    const float* a1d = (const float*)d_in[4];
    const float* b1  = (const float*)d_in[5];
    const float* W2  = (const float*)d_in[6];
    const float* a2s = (const float*)d_in[7];
    const float* a2d = (const float*)d_in[8];
    const float* b2  = (const float*)d_in[9];
    float* out = (float*)d_out;

    int N = in_sizes[0] / 128;   // 50000
    int E = in_sizes[1] / 2;     // 640000

    size_t off = 0;
    auto alloc = [&](size_t bytes) -> void* {
        off = (off + 255) & ~(size_t)255;
        void* p = (char*)d_ws + off;
        off += bytes;
        return p;
    };
    unsigned short* h = (unsigned short*)alloc((size_t)N * 128 * 2);      // bf16 h1 / h2
    unsigned short* out1b = (unsigned short*)alloc((size_t)N * 128 * 2);  // bf16 out1
    unsigned short* Wt1 = (unsigned short*)alloc(128 * 128 * 2);
    unsigned short* Wt2 = (unsigned short*)alloc(64 * 128 * 2);
    float* as_    = (float*)alloc((size_t)N * 4);
    float* ad_    = (float*)alloc((size_t)N * 4);
    int* counts   = (int*)alloc((size_t)N * 4);
    int* rowptr   = (int*)alloc((size_t)(N + 1) * 4);
    int* incl     = (int*)alloc((size_t)N * 4);
    int* bsums    = (int*)alloc(1024);
    int* colv     = (int*)alloc((size_t)E * 4);
    int* rankd    = (int*)alloc((size_t)E * 4);
    int* srcv     = (int*)alloc((size_t)E * 4);
    int* flag     = (int*)alloc(256);

    int NB = (N + 255) / 256;          // <= 256 required for in-LDS bsums scan
    int blocksN8 = (N + 7) / 8;        // 2 nodes per wave, 4 waves per block
    int rowTiles = (N + 63) / 64;
    int blocksE4 = (E + 1023) / 1024;

    int nchk = 2 * E < 512 ? 2 * E : 512;
    k_prep<<<NB + 7, 256, 0, stream>>>(counts, N, ei, nchk, flag, W1, Wt1, W2, Wt2, NB);
    k_rank<<<blocksE4, 256, 0, stream>>>(ei, flag, counts, rankd, srcv, E);
    k_scan1<<<NB, 256, 0, stream>>>(counts, incl, bsums, N);
    k_scan23<<<NB, 256, 0, stream>>>(incl, bsums, rowptr, N, NB);

    // layer 1 GEMM co-scheduled with CSR place
    k_gemm_mfma<128, true><<<rowTiles + blocksE4, 256, 0, stream>>>(
        x, Wt1, a1s, a1d, h, as_, ad_, N, rowTiles, rankd, srcv, rowptr, colv, E);
    k_agg<128, true, true><<<blocksN8, 256, 0, stream>>>(rowptr, colv, as_, ad_,
                                                         (const unsigned*)h, b1, out1b, N);

    // layer 2: Fout = 64 (A = out1b bf16); alpha fused; no place blocks
    k_gemm_mfma<64, false><<<rowTiles, 256, 0, stream>>>(
        out1b, Wt2, a2s, a2d, h, as_, ad_, N, rowTiles, rankd, srcv, rowptr, colv, 0);
    k_agg<64, false, false><<<blocksN8, 256, 0, stream>>>(rowptr, colv, as_, ad_,
                                                          (const unsigned*)h, b2, out, N);
}

// Round 14
// 137.599 us; speedup vs baseline: 1.0570x; 1.0409x over previous
//
#include <hip/hip_runtime.h>

#define LEAK 0.2f

static __device__ __forceinline__ float leaky(float e) { return e > 0.f ? e : LEAK * e; }

// bf16 helpers (RNE pack, cheap unpack)
static __device__ __forceinline__ unsigned f2bf(float f) {
    union { float f; unsigned u; } v; v.f = f;
    return (v.u + 0x7FFFu + ((v.u >> 16) & 1u)) >> 16;
}
static __device__ __forceinline__ float bflo(unsigned u) {
    union { unsigned x; float f; } v; v.x = u << 16; return v.f;
}
static __device__ __forceinline__ float bfhi(unsigned u) {
    union { unsigned x; float f; } v; v.x = u & 0xFFFF0000u; return v.f;
}

using bf16x8 = __attribute__((ext_vector_type(8))) short;
using f32x4 = __attribute__((ext_vector_type(4))) float;

// ---------------- prep: zero counts + detect edge dtype + pre-transpose W1/W2 ----------------
__global__ __launch_bounds__(256) void k_prep(int* __restrict__ counts, int n,
                                              const int* __restrict__ ei, int nwords_check,
                                              int* __restrict__ flag,
                                              const float* __restrict__ W1,
                                              unsigned short* __restrict__ Wt1,
                                              const float* __restrict__ W2,
                                              unsigned short* __restrict__ Wt2, int NB) {
    int bid = blockIdx.x;
    int t = threadIdx.x;
    if (bid == 0) {
        if (t < 64) {
            int bad = 0;
            for (int i = 1 + 2 * t; i < nwords_check; i += 128) bad |= (ei[i] != 0);
            unsigned long long anybad = __ballot(bad != 0);
            if (t == 0) *flag = (anybad == 0ULL) ? 1 : 0;  // 1 => int64 layout
        }
        return;
    }
    if (bid <= NB) {
        int i = (bid - 1) * 256 + t;
        if (i < n) counts[i] = 0;
        return;
    }
    if (bid <= NB + 4) {                 // W1: 128x128, quarter q covers 32 k
        int q = bid - (NB + 1);
        int c = t & 127, ksub = t >> 7;  // ksub 0..1
        int k0 = q * 32 + ksub * 16;
        union { unsigned short s[16]; uint4 v[2]; } u;
#pragma unroll
        for (int j = 0; j < 16; ++j) u.s[j] = (unsigned short)f2bf(W1[(size_t)(k0 + j) * 128 + c]);
        uint4* dst = (uint4*)(Wt1 + (size_t)c * 128 + k0);
        dst[0] = u.v[0];
        dst[1] = u.v[1];
        return;
    }
    {                                    // W2: 128x64, half q covers 64 k
        int q = bid - (NB + 5);
        int c = t & 63, ksub = t >> 6;   // ksub 0..3
        int k0 = q * 64 + ksub * 16;
        union { unsigned short s[16]; uint4 v[2]; } u;
#pragma unroll
        for (int j = 0; j < 16; ++j) u.s[j] = (unsigned short)f2bf(W2[(size_t)(k0 + j) * 64 + c]);
        uint4* dst = (uint4*)(Wt2 + (size_t)c * 128 + k0);
        dst[0] = u.v[0];
        dst[1] = u.v[1];
        return;
    }
}

__global__ void k_scan1(const int* __restrict__ counts, int* __restrict__ incl,
                        int* __restrict__ bsums, int n) {
    __shared__ int s[256];
    int t = threadIdx.x;
    int g = blockIdx.x * 256 + t;
    int v = (g < n) ? counts[g] : 0;
    s[t] = v;
    __syncthreads();
    for (int off = 1; off < 256; off <<= 1) {
        int add = (t >= off) ? s[t - off] : 0;
        __syncthreads();
        s[t] += add;
        __syncthreads();
    }
    if (g < n) incl[g] = s[t];
    if (t == 255) bsums[blockIdx.x] = s[255];
}

// scan2+scan3 merged: every block re-scans the <=256 bsums in LDS, then
// adds its chunk's exclusive prefix.
__global__ void k_scan23(const int* __restrict__ incl, const int* __restrict__ bsums,
                         int* __restrict__ rowptr, int n, int nb) {
    __shared__ int s[256];
    int t = threadIdx.x;
    int v = (t < nb) ? bsums[t] : 0;
    s[t] = v;
    __syncthreads();
    for (int off = 1; off < 256; off <<= 1) {
        int add = (t >= off) ? s[t - off] : 0;
        __syncthreads();
        s[t] += add;
        __syncthreads();
    }
    int pre = (blockIdx.x == 0) ? 0 : s[blockIdx.x - 1];
    int g = blockIdx.x * 256 + t;
    if (g < n) rowptr[g + 1] = incl[g] + pre;
    if (g == 0) rowptr[0] = 0;
}

// ---------------- GEMM device body (MFMA + fused alpha) ----------------
template <int F, bool AF32>
static __device__ __forceinline__ void gemm_body(const void* __restrict__ Xv,
                                                 const unsigned short* __restrict__ Wt,
                                                 const float* __restrict__ asrc,
                                                 const float* __restrict__ adst,
                                                 unsigned short* __restrict__ Hb,
                                                 float* __restrict__ out_s,
                                                 float* __restrict__ out_d, int n,
                                                 int tile, unsigned short* wsT) {
    constexpr int K = 128;
    constexpr int KP = K + 8;       // padded row length (shorts)
    constexpr int NT = F / 16;      // 16-col tiles per wave stripe
    int t = threadIdx.x;
    int w = t >> 6, lane = t & 63;
    int lrow = lane & 15, kg = lane >> 4;  // kg in 0..3
    long long row0 = (long long)tile * 64;

    // stage Wt -> LDS (linear uint4 writes into padded rows)
#pragma unroll
    for (int i = t; i < F * (K / 8); i += 256) {
        int c = i / (K / 8), j8 = i % (K / 8);
        uint4 v = ((const uint4*)(Wt + (size_t)c * K))[j8];
        *(uint4*)&wsT[c * KP + 8 * j8] = v;
    }
    __syncthreads();

    long long grow = row0 + w * 16 + lrow;
    bool rowok = grow < n;

    f32x4 acc[NT];
#pragma unroll
    for (int i = 0; i < NT; ++i) acc[i] = (f32x4){0.f, 0.f, 0.f, 0.f};

#pragma unroll
    for (int ks = 0; ks < K / 32; ++ks) {
        bf16x8 af;
        if constexpr (AF32) {
            const float* Xp = (const float*)Xv + grow * K + ks * 32 + kg * 8;
            float4 x0 = make_float4(0.f, 0.f, 0.f, 0.f), x1 = x0;
            if (rowok) {
                x0 = ((const float4*)Xp)[0];
                x1 = ((const float4*)Xp)[1];
            }
            af = (bf16x8){(short)f2bf(x0.x), (short)f2bf(x0.y), (short)f2bf(x0.z), (short)f2bf(x0.w),
                          (short)f2bf(x1.x), (short)f2bf(x1.y), (short)f2bf(x1.z), (short)f2bf(x1.w)};
        } else {
            uint4 u = make_uint4(0, 0, 0, 0);
            if (rowok) {
                const unsigned short* Xp = (const unsigned short*)Xv + grow * K + ks * 32 + kg * 8;
                u = *(const uint4*)Xp;
            }
            af = *(bf16x8*)&u;
        }
#pragma unroll
        for (int nt = 0; nt < NT; ++nt) {
            const unsigned short* bp = &wsT[(nt * 16 + lrow) * KP + ks * 32 + kg * 8];
            uint4 ub = *(const uint4*)bp;
            bf16x8 bf = *(bf16x8*)&ub;
            acc[nt] = __builtin_amdgcn_mfma_f32_16x16x32_bf16(af, bf, acc[nt], 0, 0, 0);
        }
    }

    // fused alpha: per-row dots from f32 acc
    {
        float ps[4] = {0.f, 0.f, 0.f, 0.f}, pd[4] = {0.f, 0.f, 0.f, 0.f};
#pragma unroll
        for (int nt = 0; nt < NT; ++nt) {
            float asv = asrc[nt * 16 + lrow];
            float adv = adst[nt * 16 + lrow];
#pragma unroll
            for (int i = 0; i < 4; ++i) {
                ps[i] = fmaf(acc[nt][i], asv, ps[i]);
                pd[i] = fmaf(acc[nt][i], adv, pd[i]);
            }
        }
#pragma unroll
        for (int off = 1; off < 16; off <<= 1) {
#pragma unroll
            for (int i = 0; i < 4; ++i) {
                ps[i] += __shfl_xor(ps[i], off);
                pd[i] += __shfl_xor(pd[i], off);
            }
        }
        if (lrow == 0) {
#pragma unroll
            for (int i = 0; i < 4; ++i) {
                long long r = row0 + w * 16 + kg * 4 + i;
                if (r < n) {
                    out_s[r] = ps[i];
                    out_d[r] = pd[i];
                }
            }
        }
    }

    // epilogue: D col=lane&15, row=(lane>>4)*4+reg -> bf16 scalar stores
    int r0 = w * 16 + kg * 4;
#pragma unroll
    for (int nt = 0; nt < NT; ++nt) {
        int c = nt * 16 + lrow;
#pragma unroll
        for (int i = 0; i < 4; ++i) {
            long long r = row0 + r0 + i;
            if (r < n) Hb[r * F + c] = (unsigned short)f2bf(acc[nt][i]);
        }
    }
}

// ---------------- rank device body (latency-bound atomics) ----------------
static __device__ __forceinline__ void rank_body(int auxBid, const int* __restrict__ ei,
                                                 const int* __restrict__ flag,
                                                 int* __restrict__ counts,
                                                 int* __restrict__ rankd,
                                                 int* __restrict__ srcv, int E) {
    int base = (auxBid * 256 + threadIdx.x) * 4;
    if (base >= E) return;
    int is64 = *flag;
    if (base + 3 < E) {
        int s0, s1, s2, s3, d0, d1, d2, d3;
        if (is64) {
            const uint4* ps = (const uint4*)(ei + 2 * (size_t)base);
            uint4 a = ps[0], b = ps[1];
            const uint4* pd = (const uint4*)(ei + 2 * ((size_t)E + base));
            uint4 c = pd[0], e4 = pd[1];
            s0 = a.x; s1 = a.z; s2 = b.x; s3 = b.z;
            d0 = c.x; d1 = c.z; d2 = e4.x; d3 = e4.z;
        } else {
            int4 a = *(const int4*)(ei + base);
            int4 b = *(const int4*)(ei + (size_t)E + base);
            s0 = a.x; s1 = a.y; s2 = a.z; s3 = a.w;
            d0 = b.x; d1 = b.y; d2 = b.z; d3 = b.w;
        }
        int r0 = atomicAdd(&counts[d0], 1);
        int r1 = atomicAdd(&counts[d1], 1);
        int r2 = atomicAdd(&counts[d2], 1);
        int r3 = atomicAdd(&counts[d3], 1);
        *(int4*)(rankd + base) = make_int4((r0 << 16) | d0, (r1 << 16) | d1,
                                           (r2 << 16) | d2, (r3 << 16) | d3);
        *(int4*)(srcv + base) = make_int4(s0, s1, s2, s3);
    } else {
        for (int j = 0; j < 4 && base + j < E; ++j) {
            int e = base + j;
            int ss = is64 ? ei[2 * (size_t)e] : ei[e];
            int dd = is64 ? ei[2 * ((size_t)E + e)] : ei[(size_t)E + e];
            int r = atomicAdd(&counts[dd], 1);
            rankd[e] = (r << 16) | dd;
            srcv[e] = ss;
        }
    }
}

// ---------------- place device body (latency-bound scatter) ----------------
static __device__ __forceinline__ void place_body(int auxBid, const int* __restrict__ rankd,
                                                  const int* __restrict__ srcv,
                                                  const int* __restrict__ rowptr,
                                                  int* __restrict__ colv, int E) {
    int base = (auxBid * 256 + threadIdx.x) * 4;
    if (base >= E) return;
    if (base + 3 < E) {
        int4 rd = *(const int4*)(rankd + base);
        int4 sv = *(const int4*)(srcv + base);
        int p0 = rowptr[rd.x & 0xFFFF] + (rd.x >> 16);
        int p1 = rowptr[rd.y & 0xFFFF] + (rd.y >> 16);
        int p2 = rowptr[rd.z & 0xFFFF] + (rd.z >> 16);
        int p3 = rowptr[rd.w & 0xFFFF] + (rd.w >> 16);
        colv[p0] = sv.x;
        colv[p1] = sv.y;
        colv[p2] = sv.z;
        colv[p3] = sv.w;
    } else {
        for (int j = 0; j < 4 && base + j < E; ++j) {
            int e = base + j;
            int rd = rankd[e];
            colv[rowptr[rd & 0xFFFF] + (rd >> 16)] = srcv[e];
        }
    }
}

// ---------------- GEMM co-scheduled with CSR rank ----------------
__global__ __launch_bounds__(256) void k_gemm_rank(const float* __restrict__ X,
                                                   const unsigned short* __restrict__ Wt,
                                                   const float* __restrict__ asrc,
                                                   const float* __restrict__ adst,
                                                   unsigned short* __restrict__ Hb,
                                                   float* __restrict__ out_s,
                                                   float* __restrict__ out_d, int n,
                                                   int gemmTiles, int tileBase,
                                                   const int* __restrict__ ei,
                                                   const int* __restrict__ flag,
                                                   int* __restrict__ counts,
                                                   int* __restrict__ rankd,
                                                   int* __restrict__ srcv, int E) {
    __shared__ unsigned short wsT[128 * 136];
    if (blockIdx.x >= gemmTiles) {
        rank_body(blockIdx.x - gemmTiles, ei, flag, counts, rankd, srcv, E);
        return;
    }
    gemm_body<128, true>(X, Wt, asrc, adst, Hb, out_s, out_d, n,
                         tileBase + blockIdx.x, wsT);
}

// ---------------- GEMM co-scheduled with CSR place ----------------
template <int F, bool AF32>
__global__ __launch_bounds__(256) void k_gemm_place(const void* __restrict__ Xv,
                                                    const unsigned short* __restrict__ Wt,
                                                    const float* __restrict__ asrc,
                                                    const float* __restrict__ adst,
                                                    unsigned short* __restrict__ Hb,
                                                    float* __restrict__ out_s,
                                                    float* __restrict__ out_d, int n,
                                                    int gemmTiles, int tileBase,
                                                    const int* __restrict__ rankd,
                                                    const int* __restrict__ srcv,
                                                    const int* __restrict__ rowptr,
                                                    int* __restrict__ colv, int E) {
    __shared__ unsigned short wsT[F * 136];
    if (blockIdx.x >= gemmTiles) {
        place_body(blockIdx.x - gemmTiles, rankd, srcv, rowptr, colv, E);
        return;
    }
    gemm_body<F, AF32>(Xv, Wt, asrc, adst, Hb, out_s, out_d, n,
                       tileBase + blockIdx.x, wsT);
}

// ---------------- fused segment softmax + aggregation (wave per dst node) ----------------
// (round 11 version — proven local optimum; 1 node/wave, shfl-broadcast gather)
template <int F, bool RELU, bool OB>
__global__ __launch_bounds__(256) void k_agg(const int* __restrict__ rowptr,
                                             const int* __restrict__ colv,
                                             const float* __restrict__ as_,
                                             const float* __restrict__ ad_,
                                             const unsigned* __restrict__ Hu,
                                             const float* __restrict__ bias,
                                             void* __restrict__ OUT, int n) {
    constexpr int FG8 = F / 8;       // uint4 slots per row (16 or 8)
    constexpr int GRP = 64 / FG8;    // edge-groups per wave (4 or 8)
    int node = blockIdx.x * 4 + (threadIdx.x >> 6);
    int lane = threadIdx.x & 63;
    if (node >= n) return;
    int rs = rowptr[node], re = rowptr[node + 1];
    int deg = re - rs;
    float adi = ad_[node];
    float e_self = leaky(as_[node] + adi);

    int scol = node;
    float e_l = -3.0e38f;
    if (lane < deg) {
        scol = colv[rs + lane];
        e_l = leaky(as_[scol] + adi);
    }
    float m = fmaxf(e_l, e_self);
    for (int base = 64; base < deg; base += 64) {  // rare: deg > 64
        if (base + lane < deg) m = fmaxf(m, leaky(as_[colv[rs + base + lane]] + adi));
    }
#pragma unroll
    for (int off = 32; off; off >>= 1) m = fmaxf(m, __shfl_xor(m, off));

    float p_l = (lane < deg) ? __expf(e_l - m) : 0.f;
    float ssum = p_l;
    for (int base = 64; base < deg; base += 64) {
        if (base + lane < deg) ssum += __expf(leaky(as_[colv[rs + base + lane]] + adi) - m);
    }
#pragma unroll
    for (int off = 32; off; off >>= 1) ssum += __shfl_xor(ssum, off);
    float pself = __expf(e_self - m);
    ssum += pself;
    float inv = 1.f / ssum;
    float w_l = p_l * inv;     // this lane's edge weight (first 64 edges)
    float wself = pself * inv;

    // ---- gather (bf16 rows as uint4 = 8 features) ----
    int grp = lane / FG8;      // which edge within a load step
    int fg = lane % FG8;       // which uint4 of the row
    const uint4* __restrict__ H16 = (const uint4*)Hu;
    float a0, a1, a2, a3, a4, a5, a6, a7;
    {
        uint4 hv = H16[(size_t)node * FG8 + fg];
        float ws0 = (grp == 0) ? wself : 0.f;
        a0 = ws0 * bflo(hv.x); a1 = ws0 * bfhi(hv.x);
        a2 = ws0 * bflo(hv.y); a3 = ws0 * bfhi(hv.y);
        a4 = ws0 * bflo(hv.z); a5 = ws0 * bfhi(hv.z);
        a6 = ws0 * bflo(hv.w); a7 = ws0 * bfhi(hv.w);
    }

    int cnt = deg < 64 ? deg : 64;
    constexpr int STEP = 4 * GRP;              // edges per unrolled iter (4 loads)
    int cntr = (cnt + STEP - 1) / STEP * STEP; // cnt rounded up (<= 64)
#pragma unroll 1
    for (int i = 0; i < cntr; i += STEP) {
        int i0 = i + grp, i1 = i + GRP + grp, i2 = i + 2 * GRP + grp, i3 = i + 3 * GRP + grp;
        int s0 = __shfl(scol, i0), s1 = __shfl(scol, i1);
        int s2 = __shfl(scol, i2), s3 = __shfl(scol, i3);
        float w0 = __shfl(w_l, i0), w1 = __shfl(w_l, i1);
        float w2 = __shfl(w_l, i2), w3 = __shfl(w_l, i3);
        uint4 g0 = H16[(size_t)s0 * FG8 + fg];
        uint4 g1 = H16[(size_t)s1 * FG8 + fg];
        uint4 g2 = H16[(size_t)s2 * FG8 + fg];
        uint4 g3 = H16[(size_t)s3 * FG8 + fg];
        a0 = fmaf(w0, bflo(g0.x), a0); a1 = fmaf(w0, bfhi(g0.x), a1);
        a2 = fmaf(w0, bflo(g0.y), a2); a3 = fmaf(w0, bfhi(g0.y), a3);
        a4 = fmaf(w0, bflo(g0.z), a4); a5 = fmaf(w0, bfhi(g0.z), a5);
        a6 = fmaf(w0, bflo(g0.w), a6); a7 = fmaf(w0, bfhi(g0.w), a7);
        a0 = fmaf(w1, bflo(g1.x), a0); a1 = fmaf(w1, bfhi(g1.x), a1);
        a2 = fmaf(w1, bflo(g1.y), a2); a3 = fmaf(w1, bfhi(g1.y), a3);
        a4 = fmaf(w1, bflo(g1.z), a4); a5 = fmaf(w1, bfhi(g1.z), a5);
        a6 = fmaf(w1, bflo(g1.w), a6); a7 = fmaf(w1, bfhi(g1.w), a7);
        a0 = fmaf(w2, bflo(g2.x), a0); a1 = fmaf(w2, bfhi(g2.x), a1);
        a2 = fmaf(w2, bflo(g2.y), a2); a3 = fmaf(w2, bfhi(g2.y), a3);
        a4 = fmaf(w2, bflo(g2.z), a4); a5 = fmaf(w2, bfhi(g2.z), a5);
        a6 = fmaf(w2, bflo(g2.w), a6); a7 = fmaf(w2, bfhi(g2.w), a7);
        a0 = fmaf(w3, bflo(g3.x), a0); a1 = fmaf(w3, bfhi(g3.x), a1);
        a2 = fmaf(w3, bflo(g3.y), a2); a3 = fmaf(w3, bfhi(g3.y), a3);
        a4 = fmaf(w3, bflo(g3.z), a4); a5 = fmaf(w3, bfhi(g3.z), a5);
        a6 = fmaf(w3, bflo(g3.w), a6); a7 = fmaf(w3, bfhi(g3.w), a7);
    }
    for (int j = rs + 64; j < re; ++j) {  // rare: deg > 64
        int s = colv[j];
        float w = __expf(leaky(as_[s] + adi) - m) * inv;
        float we = (grp == 0) ? w : 0.f;
        uint4 g = H16[(size_t)s * FG8 + fg];
        a0 = fmaf(we, bflo(g.x), a0); a1 = fmaf(we, bfhi(g.x), a1);
        a2 = fmaf(we, bflo(g.y), a2); a3 = fmaf(we, bfhi(g.y), a3);
        a4 = fmaf(we, bflo(g.z), a4); a5 = fmaf(we, bfhi(g.z), a5);
        a6 = fmaf(we, bflo(g.w), a6); a7 = fmaf(we, bfhi(g.w), a7);
    }
    // combine edge-groups (commutative float adds -> identical in all lanes)
#pragma unroll
    for (int off = FG8; off < 64; off <<= 1) {
        a0 += __shfl_xor(a0, off); a1 += __shfl_xor(a1, off);
        a2 += __shfl_xor(a2, off); a3 += __shfl_xor(a3, off);
        a4 += __shfl_xor(a4, off); a5 += __shfl_xor(a5, off);
        a6 += __shfl_xor(a6, off); a7 += __shfl_xor(a7, off);
    }
    if (grp == 0) {
        const float4* b4 = (const float4*)bias;
        float4 bv0 = b4[fg * 2], bv1 = b4[fg * 2 + 1];
        a0 += bv0.x; a1 += bv0.y; a2 += bv0.z; a3 += bv0.w;
        a4 += bv1.x; a5 += bv1.y; a6 += bv1.z; a7 += bv1.w;
        if (RELU) {
            a0 = fmaxf(a0, 0.f); a1 = fmaxf(a1, 0.f);
            a2 = fmaxf(a2, 0.f); a3 = fmaxf(a3, 0.f);
            a4 = fmaxf(a4, 0.f); a5 = fmaxf(a5, 0.f);
            a6 = fmaxf(a6, 0.f); a7 = fmaxf(a7, 0.f);
        }
        if (OB) {
            uint4 p;
            p.x = f2bf(a0) | (f2bf(a1) << 16);
            p.y = f2bf(a2) | (f2bf(a3) << 16);
            p.z = f2bf(a4) | (f2bf(a5) << 16);
            p.w = f2bf(a6) | (f2bf(a7) << 16);
            ((uint4*)OUT)[(size_t)node * FG8 + fg] = p;
        } else {
            float4* o4 = (float4*)((float*)OUT + (size_t)node * F + fg * 8);
            o4[0] = make_float4(a0, a1, a2, a3);
            o4[1] = make_float4(a4, a5, a6, a7);
        }
    }
}

// ---------------- host launch ----------------
extern "C" void kernel_launch(void* const* d_in, const int* in_sizes, int n_in,
                              void* d_out, int out_size, void* d_ws, size_t ws_size,
                              hipStream_t stream) {
    const float* x   = (const float*)d_in[0];
    const int*   ei  = (const int*)d_in[1];
    const float* W1  = (const float*)d_in[2];
    const float* a1s = (const float*)d_in[3];
    const float* a1d = (const float*)d_in[4];
    const float* b1  = (const float*)d_in[5];
    const float* W2  = (const float*)d_in[6];
    const float* a2s = (const float*)d_in[7];
    const float* a2d = (const float*)d_in[8];
    const float* b2  = (const float*)d_in[9];
    float* out = (float*)d_out;

    int N = in_sizes[0] / 128;   // 50000
    int E = in_sizes[1] / 2;     // 640000

    size_t off = 0;
    auto alloc = [&](size_t bytes) -> void* {
        off = (off + 255) & ~(size_t)255;
        void* p = (char*)d_ws + off;
        off += bytes;
        return p;
    };
    unsigned short* h = (unsigned short*)alloc((size_t)N * 128 * 2);      // bf16 h1 / h2
    unsigned short* out1b = (unsigned short*)alloc((size_t)N * 128 * 2);  // bf16 out1
    unsigned short* Wt1 = (unsigned short*)alloc(128 * 128 * 2);
    unsigned short* Wt2 = (unsigned short*)alloc(64 * 128 * 2);
    float* as_    = (float*)alloc((size_t)N * 4);
    float* ad_    = (float*)alloc((size_t)N * 4);
    int* counts   = (int*)alloc((size_t)N * 4);
    int* rowptr   = (int*)alloc((size_t)(N + 1) * 4);
    int* incl     = (int*)alloc((size_t)N * 4);
    int* bsums    = (int*)alloc(1024);
    int* colv     = (int*)alloc((size_t)E * 4);
    int* rankd    = (int*)alloc((size_t)E * 4);
    int* srcv     = (int*)alloc((size_t)E * 4);
    int* flag     = (int*)alloc(256);

    int NB = (N + 255) / 256;          // <= 256 required for in-LDS bsums scan
    int blocksN4 = (N + 3) / 4;
    int rowTiles = (N + 63) / 64;
    int halfTiles = (rowTiles + 1) / 2;
    int restTiles = rowTiles - halfTiles;
    int blocksE4 = (E + 1023) / 1024;

    int nchk = 2 * E < 512 ? 2 * E : 512;
    k_prep<<<NB + 7, 256, 0, stream>>>(counts, N, ei, nchk, flag, W1, Wt1, W2, Wt2, NB);

    // gemm1 first half co-scheduled with CSR rank (both depend only on prep)
    k_gemm_rank<<<halfTiles + blocksE4, 256, 0, stream>>>(
        x, Wt1, a1s, a1d, h, as_, ad_, N, halfTiles, 0,
        ei, flag, counts, rankd, srcv, E);

    k_scan1<<<NB, 256, 0, stream>>>(counts, incl, bsums, N);
    k_scan23<<<NB, 256, 0, stream>>>(incl, bsums, rowptr, N, NB);

    // gemm1 second half co-scheduled with CSR place
    k_gemm_place<128, true><<<restTiles + blocksE4, 256, 0, stream>>>(
        x, Wt1, a1s, a1d, h, as_, ad_, N, restTiles, halfTiles,
        rankd, srcv, rowptr, colv, E);

    k_agg<128, true, true><<<blocksN4, 256, 0, stream>>>(rowptr, colv, as_, ad_,
                                                         (const unsigned*)h, b1, out1b, N);

    // layer 2: Fout = 64 (A = out1b bf16); alpha fused; no aux blocks
    k_gemm_place<64, false><<<rowTiles, 256, 0, stream>>>(
        out1b, Wt2, a2s, a2d, h, as_, ad_, N, rowTiles, 0,
        rankd, srcv, rowptr, colv, 0);

    k_agg<64, false, false><<<blocksN4, 256, 0, stream>>>(rowptr, colv, as_, ad_,
                                                          (const unsigned*)h, b2, out, N);
}

// Round 15
// 134.769 us; speedup vs baseline: 1.0792x; 1.0210x over previous
//
#include <hip/hip_runtime.h>

#define LEAK 0.2f

static __device__ __forceinline__ float leaky(float e) { return e > 0.f ? e : LEAK * e; }

// bf16 helpers (RNE pack, cheap unpack)
static __device__ __forceinline__ unsigned f2bf(float f) {
    union { float f; unsigned u; } v; v.f = f;
    return (v.u + 0x7FFFu + ((v.u >> 16) & 1u)) >> 16;
}
static __device__ __forceinline__ float bflo(unsigned u) {
    union { unsigned x; float f; } v; v.x = u << 16; return v.f;
}
static __device__ __forceinline__ float bfhi(unsigned u) {
    union { unsigned x; float f; } v; v.x = u & 0xFFFF0000u; return v.f;
}

using bf16x8 = __attribute__((ext_vector_type(8))) short;
using f32x4 = __attribute__((ext_vector_type(4))) float;

// ---------------- prep: zero counts + detect edge dtype + pre-transpose W1/W2 ----------------
__global__ __launch_bounds__(256) void k_prep(int* __restrict__ counts, int n,
                                              const int* __restrict__ ei, int nwords_check,
                                              int* __restrict__ flag,
                                              const float* __restrict__ W1,
                                              unsigned short* __restrict__ Wt1,
                                              const float* __restrict__ W2,
                                              unsigned short* __restrict__ Wt2, int NB) {
    int bid = blockIdx.x;
    int t = threadIdx.x;
    if (bid == 0) {
        if (t < 64) {
            int bad = 0;
            for (int i = 1 + 2 * t; i < nwords_check; i += 128) bad |= (ei[i] != 0);
            unsigned long long anybad = __ballot(bad != 0);
            if (t == 0) *flag = (anybad == 0ULL) ? 1 : 0;  // 1 => int64 layout
        }
        return;
    }
    if (bid <= NB) {
        int i = (bid - 1) * 256 + t;
        if (i < n) counts[i] = 0;
        return;
    }
    if (bid <= NB + 4) {                 // W1: 128x128, quarter q covers 32 k
        int q = bid - (NB + 1);
        int c = t & 127, ksub = t >> 7;  // ksub 0..1
        int k0 = q * 32 + ksub * 16;
        union { unsigned short s[16]; uint4 v[2]; } u;
#pragma unroll
        for (int j = 0; j < 16; ++j) u.s[j] = (unsigned short)f2bf(W1[(size_t)(k0 + j) * 128 + c]);
        uint4* dst = (uint4*)(Wt1 + (size_t)c * 128 + k0);
        dst[0] = u.v[0];
        dst[1] = u.v[1];
        return;
    }
    {                                    // W2: 128x64, half q covers 64 k
        int q = bid - (NB + 5);
        int c = t & 63, ksub = t >> 6;   // ksub 0..3
        int k0 = q * 64 + ksub * 16;
        union { unsigned short s[16]; uint4 v[2]; } u;
#pragma unroll
        for (int j = 0; j < 16; ++j) u.s[j] = (unsigned short)f2bf(W2[(size_t)(k0 + j) * 64 + c]);
        uint4* dst = (uint4*)(Wt2 + (size_t)c * 128 + k0);
        dst[0] = u.v[0];
        dst[1] = u.v[1];
        return;
    }
}

// ---------------- CSR rank pass: r = atomicAdd(counts[d]), packed (r<<16|d) ----------------
// pack valid: N <= 65536, max degree < 32768 (here N=50000, deg ~ Poisson(12.8)).
// NOTE: runs standalone (0 LDS) — occupancy is the whole game for the
// dependent-atomic chain (round 14 lesson: LDS-taxed co-schedule = 3x slower).
__global__ __launch_bounds__(256) void k_rank(const int* __restrict__ ei,
                                              const int* __restrict__ flag,
                                              int* __restrict__ counts,
                                              int* __restrict__ rankd,
                                              int* __restrict__ srcv, int E) {
    int base = (blockIdx.x * 256 + threadIdx.x) * 4;
    if (base >= E) return;
    int is64 = *flag;
    if (base + 3 < E) {
        int s0, s1, s2, s3, d0, d1, d2, d3;
        if (is64) {
            const uint4* ps = (const uint4*)(ei + 2 * (size_t)base);
            uint4 a = ps[0], b = ps[1];
            const uint4* pd = (const uint4*)(ei + 2 * ((size_t)E + base));
            uint4 c = pd[0], e4 = pd[1];
            s0 = a.x; s1 = a.z; s2 = b.x; s3 = b.z;
            d0 = c.x; d1 = c.z; d2 = e4.x; d3 = e4.z;
        } else {
            int4 a = *(const int4*)(ei + base);
            int4 b = *(const int4*)(ei + (size_t)E + base);
            s0 = a.x; s1 = a.y; s2 = a.z; s3 = a.w;
            d0 = b.x; d1 = b.y; d2 = b.z; d3 = b.w;
        }
        int r0 = atomicAdd(&counts[d0], 1);
        int r1 = atomicAdd(&counts[d1], 1);
        int r2 = atomicAdd(&counts[d2], 1);
        int r3 = atomicAdd(&counts[d3], 1);
        *(int4*)(rankd + base) = make_int4((r0 << 16) | d0, (r1 << 16) | d1,
                                           (r2 << 16) | d2, (r3 << 16) | d3);
        *(int4*)(srcv + base) = make_int4(s0, s1, s2, s3);
    } else {
        for (int j = 0; j < 4 && base + j < E; ++j) {
            int e = base + j;
            int ss = is64 ? ei[2 * (size_t)e] : ei[e];
            int dd = is64 ? ei[2 * ((size_t)E + e)] : ei[(size_t)E + e];
            int r = atomicAdd(&counts[dd], 1);
            rankd[e] = (r << 16) | dd;
            srcv[e] = ss;
        }
    }
}

__global__ void k_scan1(const int* __restrict__ counts, int* __restrict__ incl,
                        int* __restrict__ bsums, int n) {
    __shared__ int s[256];
    int t = threadIdx.x;
    int g = blockIdx.x * 256 + t;
    int v = (g < n) ? counts[g] : 0;
    s[t] = v;
    __syncthreads();
    for (int off = 1; off < 256; off <<= 1) {
        int add = (t >= off) ? s[t - off] : 0;
        __syncthreads();
        s[t] += add;
        __syncthreads();
    }
    if (g < n) incl[g] = s[t];
    if (t == 255) bsums[blockIdx.x] = s[255];
}

// scan2+scan3 merged: every block re-scans the <=256 bsums in LDS, then
// adds its chunk's exclusive prefix.
__global__ void k_scan23(const int* __restrict__ incl, const int* __restrict__ bsums,
                         int* __restrict__ rowptr, int n, int nb) {
    __shared__ int s[256];
    int t = threadIdx.x;
    int v = (t < nb) ? bsums[t] : 0;
    s[t] = v;
    __syncthreads();
    for (int off = 1; off < 256; off <<= 1) {
        int add = (t >= off) ? s[t - off] : 0;
        __syncthreads();
        s[t] += add;
        __syncthreads();
    }
    int pre = (blockIdx.x == 0) ? 0 : s[blockIdx.x - 1];
    int g = blockIdx.x * 256 + t;
    if (g < n) rowptr[g + 1] = incl[g] + pre;
    if (g == 0) rowptr[0] = 0;
}

// ---------------- MFMA GEMM + fused alpha, with co-scheduled place blocks ----------------
// Blocks [0, rowTiles): GEMM Hb = A @ W + alpha dots (compute-bound, MFMA).
// Blocks [rowTiles, ...): CSR place colv[rowptr[d]+r]=s — fire-and-forget
// scatter tolerates the LDS-taxed occupancy (unlike rank: round 14 lesson).
template <int F, bool AF32>
__global__ __launch_bounds__(256) void k_gemm_mfma(const void* __restrict__ Xv,
                                                   const unsigned short* __restrict__ Wt,
                                                   const float* __restrict__ asrc,
                                                   const float* __restrict__ adst,
                                                   unsigned short* __restrict__ Hb,
                                                   float* __restrict__ out_s,
                                                   float* __restrict__ out_d, int n,
                                                   int rowTiles,
                                                   const int* __restrict__ rankd,
                                                   const int* __restrict__ srcv,
                                                   const int* __restrict__ rowptr,
                                                   int* __restrict__ colv, int E) {
    constexpr int K = 128;
    constexpr int KP = K + 8;       // padded row length (shorts)
    constexpr int NT = F / 16;      // 16-col tiles per wave stripe
    __shared__ unsigned short wsT[F * KP];
    int t = threadIdx.x;

    if (blockIdx.x >= rowTiles) {   // ---- place role ----
        int base = ((blockIdx.x - rowTiles) * 256 + t) * 4;
        if (base >= E) return;
        if (base + 3 < E) {
            int4 rd = *(const int4*)(rankd + base);
            int4 sv = *(const int4*)(srcv + base);
            int p0 = rowptr[rd.x & 0xFFFF] + (rd.x >> 16);
            int p1 = rowptr[rd.y & 0xFFFF] + (rd.y >> 16);
            int p2 = rowptr[rd.z & 0xFFFF] + (rd.z >> 16);
            int p3 = rowptr[rd.w & 0xFFFF] + (rd.w >> 16);
            colv[p0] = sv.x;
            colv[p1] = sv.y;
            colv[p2] = sv.z;
            colv[p3] = sv.w;
        } else {
            for (int j = 0; j < 4 && base + j < E; ++j) {
                int e = base + j;
                int rd = rankd[e];
                colv[rowptr[rd & 0xFFFF] + (rd >> 16)] = srcv[e];
            }
        }
        return;
    }

    // ---- GEMM role ----
    int w = t >> 6, lane = t & 63;
    int lrow = lane & 15, kg = lane >> 4;  // kg in 0..3
    long long row0 = (long long)blockIdx.x * 64;

#pragma unroll
    for (int i = t; i < F * (K / 8); i += 256) {
        int c = i / (K / 8), j8 = i % (K / 8);
        uint4 v = ((const uint4*)(Wt + (size_t)c * K))[j8];
        *(uint4*)&wsT[c * KP + 8 * j8] = v;
    }
    __syncthreads();

    long long grow = row0 + w * 16 + lrow;
    bool rowok = grow < n;

    f32x4 acc[NT];
#pragma unroll
    for (int i = 0; i < NT; ++i) acc[i] = (f32x4){0.f, 0.f, 0.f, 0.f};

#pragma unroll
    for (int ks = 0; ks < K / 32; ++ks) {
        bf16x8 af;
        if constexpr (AF32) {
            const float* Xp = (const float*)Xv + grow * K + ks * 32 + kg * 8;
            float4 x0 = make_float4(0.f, 0.f, 0.f, 0.f), x1 = x0;
            if (rowok) {
                x0 = ((const float4*)Xp)[0];
                x1 = ((const float4*)Xp)[1];
            }
            af = (bf16x8){(short)f2bf(x0.x), (short)f2bf(x0.y), (short)f2bf(x0.z), (short)f2bf(x0.w),
                          (short)f2bf(x1.x), (short)f2bf(x1.y), (short)f2bf(x1.z), (short)f2bf(x1.w)};
        } else {
            uint4 u = make_uint4(0, 0, 0, 0);
            if (rowok) {
                const unsigned short* Xp = (const unsigned short*)Xv + grow * K + ks * 32 + kg * 8;
                u = *(const uint4*)Xp;
            }
            af = *(bf16x8*)&u;
        }
#pragma unroll
        for (int nt = 0; nt < NT; ++nt) {
            const unsigned short* bp = &wsT[(nt * 16 + lrow) * KP + ks * 32 + kg * 8];
            uint4 ub = *(const uint4*)bp;
            bf16x8 bf = *(bf16x8*)&ub;
            acc[nt] = __builtin_amdgcn_mfma_f32_16x16x32_bf16(af, bf, acc[nt], 0, 0, 0);
        }
    }

    // fused alpha
    {
        float ps[4] = {0.f, 0.f, 0.f, 0.f}, pd[4] = {0.f, 0.f, 0.f, 0.f};
#pragma unroll
        for (int nt = 0; nt < NT; ++nt) {
            float asv = asrc[nt * 16 + lrow];
            float adv = adst[nt * 16 + lrow];
#pragma unroll
            for (int i = 0; i < 4; ++i) {
                ps[i] = fmaf(acc[nt][i], asv, ps[i]);
                pd[i] = fmaf(acc[nt][i], adv, pd[i]);
            }
        }
#pragma unroll
        for (int off = 1; off < 16; off <<= 1) {
#pragma unroll
            for (int i = 0; i < 4; ++i) {
                ps[i] += __shfl_xor(ps[i], off);
                pd[i] += __shfl_xor(pd[i], off);
            }
        }
        if (lrow == 0) {
#pragma unroll
            for (int i = 0; i < 4; ++i) {
                long long r = row0 + w * 16 + kg * 4 + i;
                if (r < n) {
                    out_s[r] = ps[i];
                    out_d[r] = pd[i];
                }
            }
        }
    }

    int r0 = w * 16 + kg * 4;
#pragma unroll
    for (int nt = 0; nt < NT; ++nt) {
        int c = nt * 16 + lrow;
#pragma unroll
        for (int i = 0; i < 4; ++i) {
            long long r = row0 + r0 + i;
            if (r < n) Hb[r * F + c] = (unsigned short)f2bf(acc[nt][i]);
        }
    }
}

// ---------------- fused segment softmax + aggregation (wave per dst node) ----------------
// 1 node/wave, shfl-broadcast gather — proven local optimum (rounds 12/13
// fusion and 2-node variants both regressed via occupancy loss).
template <int F, bool RELU, bool OB>
__global__ __launch_bounds__(256) void k_agg(const int* __restrict__ rowptr,
                                             const int* __restrict__ colv,
                                             const float* __restrict__ as_,
                                             const float* __restrict__ ad_,
                                             const unsigned* __restrict__ Hu,
                                             const float* __restrict__ bias,
                                             void* __restrict__ OUT, int n) {
    constexpr int FG8 = F / 8;       // uint4 slots per row (16 or 8)
    constexpr int GRP = 64 / FG8;    // edge-groups per wave (4 or 8)
    int node = blockIdx.x * 4 + (threadIdx.x >> 6);
    int lane = threadIdx.x & 63;
    if (node >= n) return;
    int rs = rowptr[node], re = rowptr[node + 1];
    int deg = re - rs;
    float adi = ad_[node];
    float e_self = leaky(as_[node] + adi);

    int scol = node;
    float e_l = -3.0e38f;
    if (lane < deg) {
        scol = colv[rs + lane];
        e_l = leaky(as_[scol] + adi);
    }
    float m = fmaxf(e_l, e_self);
    for (int base = 64; base < deg; base += 64) {  // rare: deg > 64
        if (base + lane < deg) m = fmaxf(m, leaky(as_[colv[rs + base + lane]] + adi));
    }
#pragma unroll
    for (int off = 32; off; off >>= 1) m = fmaxf(m, __shfl_xor(m, off));

    float p_l = (lane < deg) ? __expf(e_l - m) : 0.f;
    float ssum = p_l;
    for (int base = 64; base < deg; base += 64) {
        if (base + lane < deg) ssum += __expf(leaky(as_[colv[rs + base + lane]] + adi) - m);
    }
#pragma unroll
    for (int off = 32; off; off >>= 1) ssum += __shfl_xor(ssum, off);
    float pself = __expf(e_self - m);
    ssum += pself;
    float inv = 1.f / ssum;
    float w_l = p_l * inv;     // this lane's edge weight (first 64 edges)
    float wself = pself * inv;

    // ---- gather (bf16 rows as uint4 = 8 features) ----
    int grp = lane / FG8;      // which edge within a load step
    int fg = lane % FG8;       // which uint4 of the row
    const uint4* __restrict__ H16 = (const uint4*)Hu;
    float a0, a1, a2, a3, a4, a5, a6, a7;
    {
        uint4 hv = H16[(size_t)node * FG8 + fg];
        float ws0 = (grp == 0) ? wself : 0.f;
        a0 = ws0 * bflo(hv.x); a1 = ws0 * bfhi(hv.x);
        a2 = ws0 * bflo(hv.y); a3 = ws0 * bfhi(hv.y);
        a4 = ws0 * bflo(hv.z); a5 = ws0 * bfhi(hv.z);
        a6 = ws0 * bflo(hv.w); a7 = ws0 * bfhi(hv.w);
    }

    int cnt = deg < 64 ? deg : 64;
    constexpr int STEP = 4 * GRP;              // edges per unrolled iter (4 loads)
    int cntr = (cnt + STEP - 1) / STEP * STEP; // cnt rounded up (<= 64)
#pragma unroll 1
    for (int i = 0; i < cntr; i += STEP) {
        int i0 = i + grp, i1 = i + GRP + grp, i2 = i + 2 * GRP + grp, i3 = i + 3 * GRP + grp;
        int s0 = __shfl(scol, i0), s1 = __shfl(scol, i1);
        int s2 = __shfl(scol, i2), s3 = __shfl(scol, i3);
        float w0 = __shfl(w_l, i0), w1 = __shfl(w_l, i1);
        float w2 = __shfl(w_l, i2), w3 = __shfl(w_l, i3);
        uint4 g0 = H16[(size_t)s0 * FG8 + fg];
        uint4 g1 = H16[(size_t)s1 * FG8 + fg];
        uint4 g2 = H16[(size_t)s2 * FG8 + fg];
        uint4 g3 = H16[(size_t)s3 * FG8 + fg];
        a0 = fmaf(w0, bflo(g0.x), a0); a1 = fmaf(w0, bfhi(g0.x), a1);
        a2 = fmaf(w0, bflo(g0.y), a2); a3 = fmaf(w0, bfhi(g0.y), a3);
        a4 = fmaf(w0, bflo(g0.z), a4); a5 = fmaf(w0, bfhi(g0.z), a5);
        a6 = fmaf(w0, bflo(g0.w), a6); a7 = fmaf(w0, bfhi(g0.w), a7);
        a0 = fmaf(w1, bflo(g1.x), a0); a1 = fmaf(w1, bfhi(g1.x), a1);
        a2 = fmaf(w1, bflo(g1.y), a2); a3 = fmaf(w1, bfhi(g1.y), a3);
        a4 = fmaf(w1, bflo(g1.z), a4); a5 = fmaf(w1, bfhi(g1.z), a5);
        a6 = fmaf(w1, bflo(g1.w), a6); a7 = fmaf(w1, bfhi(g1.w), a7);
        a0 = fmaf(w2, bflo(g2.x), a0); a1 = fmaf(w2, bfhi(g2.x), a1);
        a2 = fmaf(w2, bflo(g2.y), a2); a3 = fmaf(w2, bfhi(g2.y), a3);
        a4 = fmaf(w2, bflo(g2.z), a4); a5 = fmaf(w2, bfhi(g2.z), a5);
        a6 = fmaf(w2, bflo(g2.w), a6); a7 = fmaf(w2, bfhi(g2.w), a7);
        a0 = fmaf(w3, bflo(g3.x), a0); a1 = fmaf(w3, bfhi(g3.x), a1);
        a2 = fmaf(w3, bflo(g3.y), a2); a3 = fmaf(w3, bfhi(g3.y), a3);
        a4 = fmaf(w3, bflo(g3.z), a4); a5 = fmaf(w3, bfhi(g3.z), a5);
        a6 = fmaf(w3, bflo(g3.w), a6); a7 = fmaf(w3, bfhi(g3.w), a7);
    }
    for (int j = rs + 64; j < re; ++j) {  // rare: deg > 64
        int s = colv[j];
        float w = __expf(leaky(as_[s] + adi) - m) * inv;
        float we = (grp == 0) ? w : 0.f;
        uint4 g = H16[(size_t)s * FG8 + fg];
        a0 = fmaf(we, bflo(g.x), a0); a1 = fmaf(we, bfhi(g.x), a1);
        a2 = fmaf(we, bflo(g.y), a2); a3 = fmaf(we, bfhi(g.y), a3);
        a4 = fmaf(we, bflo(g.z), a4); a5 = fmaf(we, bfhi(g.z), a5);
        a6 = fmaf(we, bflo(g.w), a6); a7 = fmaf(we, bfhi(g.w), a7);
    }
    // combine edge-groups (commutative float adds -> identical in all lanes)
#pragma unroll
    for (int off = FG8; off < 64; off <<= 1) {
        a0 += __shfl_xor(a0, off); a1 += __shfl_xor(a1, off);
        a2 += __shfl_xor(a2, off); a3 += __shfl_xor(a3, off);
        a4 += __shfl_xor(a4, off); a5 += __shfl_xor(a5, off);
        a6 += __shfl_xor(a6, off); a7 += __shfl_xor(a7, off);
    }
    if (grp == 0) {
        const float4* b4 = (const float4*)bias;
        float4 bv0 = b4[fg * 2], bv1 = b4[fg * 2 + 1];
        a0 += bv0.x; a1 += bv0.y; a2 += bv0.z; a3 += bv0.w;
        a4 += bv1.x; a5 += bv1.y; a6 += bv1.z; a7 += bv1.w;
        if (RELU) {
            a0 = fmaxf(a0, 0.f); a1 = fmaxf(a1, 0.f);
            a2 = fmaxf(a2, 0.f); a3 = fmaxf(a3, 0.f);
            a4 = fmaxf(a4, 0.f); a5 = fmaxf(a5, 0.f);
            a6 = fmaxf(a6, 0.f); a7 = fmaxf(a7, 0.f);
        }
        if (OB) {
            uint4 p;
            p.x = f2bf(a0) | (f2bf(a1) << 16);
            p.y = f2bf(a2) | (f2bf(a3) << 16);
            p.z = f2bf(a4) | (f2bf(a5) << 16);
            p.w = f2bf(a6) | (f2bf(a7) << 16);
            ((uint4*)OUT)[(size_t)node * FG8 + fg] = p;
        } else {
            float4* o4 = (float4*)((float*)OUT + (size_t)node * F + fg * 8);
            o4[0] = make_float4(a0, a1, a2, a3);
            o4[1] = make_float4(a4, a5, a6, a7);
        }
    }
}

// ---------------- host launch ----------------
extern "C" void kernel_launch(void* const* d_in, const int* in_sizes, int n_in,
                              void* d_out, int out_size, void* d_ws, size_t ws_size,
                              hipStream_t stream) {
    const float* x   = (const float*)d_in[0];
    const int*   ei  = (const int*)d_in[1];
    const float* W1  = (const float*)d_in[2];
    const float* a1s = (const float*)d_in[3];
    const float* a1d = (const float*)d_in[4];
    const float* b1  = (const float*)d_in[5];
    const float* W2  = (const float*)d_in[6];
    const float* a2s = (const float*)d_in[7];
    const float* a2d = (const float*)d_in[8];
    const float* b2  = (const float*)d_in[9];
    float* out = (float*)d_out;

    int N = in_sizes[0] / 128;   // 50000
    int E = in_sizes[1] / 2;     // 640000

    size_t off = 0;
    auto alloc = [&](size_t bytes) -> void* {
        off = (off + 255) & ~(size_t)255;
        void* p = (char*)d_ws + off;
        off += bytes;
        return p;
    };
    unsigned short* h = (unsigned short*)alloc((size_t)N * 128 * 2);      // bf16 h1 / h2
    unsigned short* out1b = (unsigned short*)alloc((size_t)N * 128 * 2);  // bf16 out1
    unsigned short* Wt1 = (unsigned short*)alloc(128 * 128 * 2);
    unsigned short* Wt2 = (unsigned short*)alloc(64 * 128 * 2);
    float* as_    = (float*)alloc((size_t)N * 4);
    float* ad_    = (float*)alloc((size_t)N * 4);
    int* counts   = (int*)alloc((size_t)N * 4);
    int* rowptr   = (int*)alloc((size_t)(N + 1) * 4);
    int* incl     = (int*)alloc((size_t)N * 4);
    int* bsums    = (int*)alloc(1024);
    int* colv     = (int*)alloc((size_t)E * 4);
    int* rankd    = (int*)alloc((size_t)E * 4);
    int* srcv     = (int*)alloc((size_t)E * 4);
    int* flag     = (int*)alloc(256);

    int NB = (N + 255) / 256;          // <= 256 required for in-LDS bsums scan
    int blocksN4 = (N + 3) / 4;
    int rowTiles = (N + 63) / 64;
    int blocksE4 = (E + 1023) / 1024;

    int nchk = 2 * E < 512 ? 2 * E : 512;
    k_prep<<<NB + 7, 256, 0, stream>>>(counts, N, ei, nchk, flag, W1, Wt1, W2, Wt2, NB);
    k_rank<<<blocksE4, 256, 0, stream>>>(ei, flag, counts, rankd, srcv, E);
    k_scan1<<<NB, 256, 0, stream>>>(counts, incl, bsums, N);
    k_scan23<<<NB, 256, 0, stream>>>(incl, bsums, rowptr, N, NB);

    // layer 1 GEMM co-scheduled with CSR place (independent work, one dispatch)
    k_gemm_mfma<128, true><<<rowTiles + blocksE4, 256, 0, stream>>>(
        x, Wt1, a1s, a1d, h, as_, ad_, N, rowTiles, rankd, srcv, rowptr, colv, E);
    k_agg<128, true, true><<<blocksN4, 256, 0, stream>>>(rowptr, colv, as_, ad_,
                                                         (const unsigned*)h, b1, out1b, N);

    // layer 2: Fout = 64 (A = out1b bf16); alpha fused; no place blocks
    k_gemm_mfma<64, false><<<rowTiles, 256, 0, stream>>>(
        out1b, Wt2, a2s, a2d, h, as_, ad_, N, rowTiles, rankd, srcv, rowptr, colv, 0);
    k_agg<64, false, false><<<blocksN4, 256, 0, stream>>>(rowptr, colv, as_, ad_,
                                                          (const unsigned*)h, b2, out, N);
}